// Round 3
// baseline (5732.576 us; speedup 1.0000x reference)
//
#include <hip/hip_runtime.h>
#include <math.h>

#define LMAXS 1024
#define NB 8
#define DIM 512
#define HEADS 8
#define DH 64
#define DEPTH 6
#define MLP 2048
#define NC 1000
#define PDIM 768
#define MPACK 5376   // 5360 valid rows padded to 42*128
#define MVALID 5360

typedef __attribute__((ext_vector_type(8))) short short8;
typedef __attribute__((ext_vector_type(4))) float floatx4;
typedef unsigned short ushort;

// per-image patch grid width, valid token count L, packed row offset
__constant__ int c_w[8]   = {32,24,32,24,28,32,16,20};
__constant__ int c_L[8]   = {1024,768,896,576,560,512,384,640};
__constant__ int c_off[9] = {0,1024,1792,2688,3264,3824,4336,4720,5360};

__device__ __forceinline__ int row2img(int r) {
  int b = 0;
  #pragma unroll
  for (int i = 1; i < 8; ++i) if (r >= c_off[i]) b = i;
  return b;
}

__device__ __forceinline__ ushort f2bf(float x) {
  unsigned int u = __float_as_uint(x);
  u += 0x7fff + ((u >> 16) & 1);          // RNE
  return (ushort)(u >> 16);
}

// ---- block-wide (256 thr) sum + sumsq reduction ----
__device__ __forceinline__ void reduce2_256(float& s, float& s2, float* red) {
  #pragma unroll
  for (int off = 32; off; off >>= 1) {
    s  += __shfl_xor(s, off);
    s2 += __shfl_xor(s2, off);
  }
  int wv = threadIdx.x >> 6;
  if ((threadIdx.x & 63) == 0) { red[wv*2] = s; red[wv*2+1] = s2; }
  __syncthreads();
  s  = red[0] + red[2] + red[4] + red[6];
  s2 = red[1] + red[3] + red[5] + red[7];
  __syncthreads();
}

// ---- patchify + LN(768), packed rows: one block per valid token ----
__global__ __launch_bounds__(256) void pack_ln1_k(
    const float* __restrict__ images, const float* __restrict__ g,
    const float* __restrict__ bb, float* __restrict__ tok) {
  int r = blockIdx.x;
  float* out = tok + (size_t)r * PDIM;
  if (r >= MVALID) {                       // alignment tail: keep GEMM input finite
    for (int i = threadIdx.x; i < PDIM; i += 256) out[i] = 0.f;
    return;
  }
  int b = row2img(r), l = r - c_off[b];
  int wgrid = c_w[b];
  __shared__ float vals[PDIM];
  __shared__ float red[8];
  int hp = l / wgrid, wp = l % wgrid;
  const float* base = images + (size_t)b*3*512*512 + (size_t)hp*16*512 + wp*16;
  float s = 0.f, s2 = 0.f;
  for (int i = threadIdx.x; i < PDIM; i += 256) {
    int c = i >> 8, rr = (i >> 4) & 15, cc = i & 15;
    float v = base[(size_t)c*512*512 + rr*512 + cc];
    vals[i] = v; s += v; s2 += v*v;
  }
  reduce2_256(s, s2, red);
  float mu = s * (1.f/PDIM);
  float rs = rsqrtf(fmaxf(s2*(1.f/PDIM) - mu*mu, 0.f) + 1e-5f);
  for (int i = threadIdx.x; i < PDIM; i += 256)
    out[i] = (vals[i]-mu)*rs*g[i] + bb[i];
}

// ---- generic fp32 GEMM: C[M,N] (+)= act(A[M,K] @ W[N,K]^T + bias) ----
template<int ACT, int ACC>
__global__ __launch_bounds__(256) void gemm_nt(
    const float* __restrict__ A, const float* __restrict__ W,
    const float* __restrict__ bias, float* __restrict__ C,
    int M, int N, int K) {
  __shared__ float As[16][128];
  __shared__ float Ws[16][128];
  int tid = threadIdx.x;
  int tx = tid & 15, ty = tid >> 4;
  int row0 = blockIdx.y * 128, col0 = blockIdx.x * 128;
  int lr = tid >> 1, lk = (tid & 1) * 8;
  const float* Ap = A + (size_t)(row0 + lr) * K + lk;
  const float* Wp = W + (size_t)(col0 + lr) * K + lk;
  float acc[8][8] = {};
  for (int k0 = 0; k0 < K; k0 += 16) {
    float4 a0 = *(const float4*)(Ap + k0);
    float4 a1 = *(const float4*)(Ap + k0 + 4);
    float4 w0 = *(const float4*)(Wp + k0);
    float4 w1 = *(const float4*)(Wp + k0 + 4);
    __syncthreads();
    As[lk+0][lr]=a0.x; As[lk+1][lr]=a0.y; As[lk+2][lr]=a0.z; As[lk+3][lr]=a0.w;
    As[lk+4][lr]=a1.x; As[lk+5][lr]=a1.y; As[lk+6][lr]=a1.z; As[lk+7][lr]=a1.w;
    Ws[lk+0][lr]=w0.x; Ws[lk+1][lr]=w0.y; Ws[lk+2][lr]=w0.z; Ws[lk+3][lr]=w0.w;
    Ws[lk+4][lr]=w1.x; Ws[lk+5][lr]=w1.y; Ws[lk+6][lr]=w1.z; Ws[lk+7][lr]=w1.w;
    __syncthreads();
    #pragma unroll
    for (int kk = 0; kk < 16; ++kk) {
      float a[8], bb[8];
      #pragma unroll
      for (int i = 0; i < 8; ++i) a[i] = As[kk][ty*8+i];
      #pragma unroll
      for (int j = 0; j < 8; ++j) bb[j] = Ws[kk][tx*8+j];
      #pragma unroll
      for (int i = 0; i < 8; ++i)
        #pragma unroll
        for (int j = 0; j < 8; ++j)
          acc[i][j] += a[i]*bb[j];
    }
  }
  #pragma unroll
  for (int i = 0; i < 8; ++i) {
    int r = row0 + ty*8 + i;
    float* cp = C + (size_t)r * N + col0 + tx*8;
    #pragma unroll
    for (int j = 0; j < 8; ++j) {
      float v = acc[i][j];
      if (bias) v += bias[col0 + tx*8 + j];
      if (ACT == 1) v = 0.5f*v*(1.f + erff(v*0.70710678118654752f));
      if (ACC) cp[j] += v; else cp[j] = v;
    }
  }
}

// ---- row LayerNorm (width n), X->Y ----
__global__ __launch_bounds__(256) void row_ln_k(
    const float* __restrict__ X, const float* __restrict__ g,
    float* __restrict__ Y, int n) {
  __shared__ float red[8];
  size_t base = (size_t)blockIdx.x * n;
  float s=0.f, s2=0.f;
  for (int i = threadIdx.x; i < n; i += 256) { float v = X[base+i]; s += v; s2 += v*v; }
  reduce2_256(s, s2, red);
  float mu = s/n, rs = rsqrtf(fmaxf(s2/n - mu*mu, 0.f) + 1e-5f);
  for (int i = threadIdx.x; i < n; i += 256)
    Y[base+i] = (X[base+i]-mu)*rs*g[i];
}

// ---- LN2 + bias + pos embed, packed, in place on T ----
__global__ __launch_bounds__(256) void ln2_pos_k(
    float* __restrict__ T, const float* __restrict__ g, const float* __restrict__ bb,
    const float* __restrict__ ph, const float* __restrict__ pw) {
  int r = blockIdx.x;
  float* x = T + (size_t)r * DIM;
  if (r >= MVALID) {
    for (int i = threadIdx.x; i < DIM; i += 256) x[i] = 0.f;
    return;
  }
  int b = row2img(r), l = r - c_off[b];
  __shared__ float red[8];
  int wgrid = c_w[b];
  int hi = l / wgrid, wi = l % wgrid;
  float s=0.f, s2=0.f;
  for (int i = threadIdx.x; i < DIM; i += 256) { float v = x[i]; s+=v; s2+=v*v; }
  reduce2_256(s, s2, red);
  float mu = s*(1.f/DIM), rs = rsqrtf(fmaxf(s2*(1.f/DIM)-mu*mu, 0.f)+1e-5f);
  for (int i = threadIdx.x; i < DIM; i += 256)
    x[i] = (x[i]-mu)*rs*g[i] + bb[i] + ph[hi*DIM+i] + pw[wi*DIM+i];
}

// ---- per-head LN over DH=64, one wave per row (for pool K) ----
__global__ __launch_bounds__(256) void head_ln_k(float* __restrict__ X, const float* __restrict__ g) {
  int row = blockIdx.x*4 + (threadIdx.x >> 6);
  int lane = threadIdx.x & 63;
  float* x = X + (size_t)row * DH;
  float v = x[lane];
  float s = v, s2 = v*v;
  #pragma unroll
  for (int off=32; off; off>>=1) { s += __shfl_xor(s,off); s2 += __shfl_xor(s2,off); }
  float mu = s*(1.f/DH), rs = rsqrtf(fmaxf(s2*(1.f/DH)-mu*mu, 0.f)+1e-5f);
  x[lane] = (v-mu)*rs*g[lane];
}

// ---- QKV split to per-head bf16 [b,h,l,64] with fused head-LN on Q,K ----
__global__ __launch_bounds__(512) void split_ln_k(
    const float* __restrict__ Qb, const float* __restrict__ Kb, const float* __restrict__ Vb,
    const float* __restrict__ qn, const float* __restrict__ kn,
    ushort* __restrict__ Qh, ushort* __restrict__ Kh, ushort* __restrict__ Vh) {
  int r = blockIdx.x;                  // 0..MVALID-1
  int h = threadIdx.x >> 6, lane = threadIdx.x & 63;
  int b = row2img(r), l = r - c_off[b];
  size_t src = (size_t)r*DIM + h*DH + lane;
  size_t dst = ((size_t)(b*8+h)*LMAXS + l)*DH + lane;
  float v, s, s2, mu, rs;

  v = Qb[src]; s = v; s2 = v*v;
  #pragma unroll
  for (int off=32; off; off>>=1) { s += __shfl_xor(s,off); s2 += __shfl_xor(s2,off); }
  mu = s*(1.f/DH); rs = rsqrtf(fmaxf(s2*(1.f/DH)-mu*mu,0.f)+1e-5f);
  Qh[dst] = f2bf((v-mu)*rs*qn[lane]);

  v = Kb[src]; s = v; s2 = v*v;
  #pragma unroll
  for (int off=32; off; off>>=1) { s += __shfl_xor(s,off); s2 += __shfl_xor(s2,off); }
  mu = s*(1.f/DH); rs = rsqrtf(fmaxf(s2*(1.f/DH)-mu*mu,0.f)+1e-5f);
  Kh[dst] = f2bf((v-mu)*rs*kn[lane]);

  Vh[dst] = f2bf(Vb[src]);
}

// ---- bf16 MFMA flash attention ----
// grid.x = b*8+h (64), grid.y = q-tile of 64 (16). Block 256 = 4 waves, wave = 16 queries.
// LDS: K chunk [64k][72d] bf16, V^T chunk [64d][72k] bf16, P per-wave [16q][72k] bf16.
__global__ __launch_bounds__(256) void attn_mfma_k(
    const ushort* __restrict__ Qh, const ushort* __restrict__ Kh,
    const ushort* __restrict__ Vh, float* __restrict__ O) {
  int bh = blockIdx.x, b = bh >> 3, h = bh & 7;
  int Lb = c_L[b];
  int qt = blockIdx.y;
  if (qt * 64 >= Lb) return;
  __shared__ ushort Ks[64][72];
  __shared__ ushort Vt[64][72];
  __shared__ ushort Pb[4][16][72];
  int tid = threadIdx.x, wv = tid >> 6, lane = tid & 63;
  int quad = lane >> 4, l15 = lane & 15;
  int q0 = qt*64 + wv*16;
  bool active = q0 < Lb;               // L % 16 == 0 for all images: no partial wave tiles
  const ushort* qhb = Qh + (size_t)bh * LMAXS * DH;
  const ushort* khb = Kh + (size_t)bh * LMAXS * DH;
  const ushort* vhb = Vh + (size_t)bh * LMAXS * DH;
  short8 aq0 = {}, aq1 = {};
  if (active) {
    const ushort* qp = qhb + (size_t)(q0 + l15) * DH;
    aq0 = *(const short8*)(qp + quad*8);
    aq1 = *(const short8*)(qp + 32 + quad*8);
  }
  float mrow[4] = {-1e30f,-1e30f,-1e30f,-1e30f};
  float lrow[4] = {0.f,0.f,0.f,0.f};
  floatx4 o[4] = {};
  int krow = tid >> 2, dcol = (tid & 3) * 16;   // staging: 4 threads per key row
  for (int kc = 0; kc < Lb; kc += 64) {
    __syncthreads();
    const ushort* kr = khb + (size_t)(kc + krow) * DH + dcol;
    *(short8*)&Ks[krow][dcol]   = *(const short8*)kr;
    *(short8*)&Ks[krow][dcol+8] = *(const short8*)(kr + 8);
    const ushort* vr = vhb + (size_t)(kc + krow) * DH + dcol;
    short8 v0 = *(const short8*)vr;
    short8 v1 = *(const short8*)(vr + 8);
    #pragma unroll
    for (int j = 0; j < 8; ++j) Vt[dcol+j][krow]   = (ushort)v0[j];
    #pragma unroll
    for (int j = 0; j < 8; ++j) Vt[dcol+8+j][krow] = (ushort)v1[j];
    __syncthreads();
    if (!active) continue;
    floatx4 sv[4];
    #pragma unroll
    for (int kb = 0; kb < 4; ++kb) {
      floatx4 s = {};
      s = __builtin_amdgcn_mfma_f32_16x16x32_bf16(aq0, *(const short8*)&Ks[kb*16+l15][quad*8], s, 0,0,0);
      s = __builtin_amdgcn_mfma_f32_16x16x32_bf16(aq1, *(const short8*)&Ks[kb*16+l15][32+quad*8], s, 0,0,0);
      sv[kb] = s;
    }
    bool tail = (kc + 64 > Lb);
    float rmax[4] = {-1e30f,-1e30f,-1e30f,-1e30f};
    #pragma unroll
    for (int kb = 0; kb < 4; ++kb)
      #pragma unroll
      for (int reg = 0; reg < 4; ++reg) {
        float x = sv[kb][reg] * 0.125f;
        if (tail && (kc + kb*16 + l15 >= Lb)) x = -1e9f;
        sv[kb][reg] = x;
        rmax[reg] = fmaxf(rmax[reg], x);
      }
    #pragma unroll
    for (int reg = 0; reg < 4; ++reg) {
      #pragma unroll
      for (int off = 1; off < 16; off <<= 1) rmax[reg] = fmaxf(rmax[reg], __shfl_xor(rmax[reg], off));
    }
    float alpha[4], rsum[4] = {0.f,0.f,0.f,0.f};
    #pragma unroll
    for (int reg = 0; reg < 4; ++reg) {
      float mn = fmaxf(mrow[reg], rmax[reg]);
      alpha[reg] = __expf(mrow[reg] - mn);
      mrow[reg] = mn;
    }
    #pragma unroll
    for (int kb = 0; kb < 4; ++kb)
      #pragma unroll
      for (int reg = 0; reg < 4; ++reg) {
        float p = __expf(sv[kb][reg] - mrow[reg]);
        rsum[reg] += p;
        Pb[wv][quad*4+reg][kb*16+l15] = f2bf(p);
      }
    #pragma unroll
    for (int reg = 0; reg < 4; ++reg) {
      #pragma unroll
      for (int off = 1; off < 16; off <<= 1) rsum[reg] += __shfl_xor(rsum[reg], off);
      lrow[reg] = lrow[reg]*alpha[reg] + rsum[reg];
    }
    #pragma unroll
    for (int nb = 0; nb < 4; ++nb)
      #pragma unroll
      for (int reg = 0; reg < 4; ++reg) o[nb][reg] *= alpha[reg];
    short8 a0 = *(const short8*)&Pb[wv][l15][quad*8];
    short8 a1 = *(const short8*)&Pb[wv][l15][32+quad*8];
    #pragma unroll
    for (int nb = 0; nb < 4; ++nb) {
      o[nb] = __builtin_amdgcn_mfma_f32_16x16x32_bf16(a0, *(const short8*)&Vt[nb*16+l15][quad*8], o[nb], 0,0,0);
      o[nb] = __builtin_amdgcn_mfma_f32_16x16x32_bf16(a1, *(const short8*)&Vt[nb*16+l15][32+quad*8], o[nb], 0,0,0);
    }
  }
  if (active) {
    int rbase = c_off[b] + q0 + quad*4;
    #pragma unroll
    for (int nb = 0; nb < 4; ++nb)
      #pragma unroll
      for (int reg = 0; reg < 4; ++reg)
        O[(size_t)(rbase+reg)*DIM + h*DH + nb*16 + l15] = o[nb][reg] / lrow[reg];
  }
}

// ---- pool query: LN(pool_q) @ pool_wq^T then per-head LN ----
__global__ __launch_bounds__(256) void pool_prep_k(
    const float* __restrict__ pq, const float* __restrict__ pln,
    const float* __restrict__ pwq, const float* __restrict__ pqn,
    float* __restrict__ qout) {
  __shared__ float qln[DIM];
  __shared__ float qp[DIM];
  __shared__ float red[8];
  __shared__ float hstat[16];
  int tid = threadIdx.x;
  float s=0.f, s2=0.f;
  for (int i=tid;i<DIM;i+=256){ float v=pq[i]; s+=v; s2+=v*v; }
  reduce2_256(s, s2, red);
  float mu=s*(1.f/DIM), rs=rsqrtf(fmaxf(s2*(1.f/DIM)-mu*mu,0.f)+1e-5f);
  for (int i=tid;i<DIM;i+=256) qln[i]=(pq[i]-mu)*rs*pln[i];
  __syncthreads();
  for (int n=tid;n<DIM;n+=256) {
    const float4* wr = (const float4*)(pwq + (size_t)n*DIM);
    float a=0.f;
    for (int k=0;k<DIM/4;++k) {
      float4 w4 = wr[k];
      float4 q4 = *(const float4*)&qln[k*4];
      a += w4.x*q4.x + w4.y*q4.y + w4.z*q4.z + w4.w*q4.w;
    }
    qp[n]=a;
  }
  __syncthreads();
  if (tid < 8) {
    float hs=0.f, hs2=0.f;
    for (int i=0;i<64;++i){ float v=qp[tid*64+i]; hs+=v; hs2+=v*v; }
    float hmu=hs*(1.f/64), hv=hs2*(1.f/64)-hmu*hmu;
    hstat[tid*2]=hmu; hstat[tid*2+1]=rsqrtf(fmaxf(hv,0.f)+1e-5f);
  }
  __syncthreads();
  for (int i=tid;i<DIM;i+=256) {
    int hh=i>>6;
    qout[i]=(qp[i]-hstat[hh*2])*hstat[hh*2+1]*pqn[i&63];
  }
}

// ---- pooling cross-attention over packed keys ----
__global__ __launch_bounds__(256) void pool_attn_k(
    const float* __restrict__ qpool, const float* __restrict__ Kb,
    const float* __restrict__ Vb, float* __restrict__ O) {
  __shared__ float ss[LMAXS];
  __shared__ float qh[DH];
  __shared__ float red[4];
  __shared__ float part[4][DH];
  int bh = blockIdx.x, b = bh>>3, h = bh&7;
  int tid = threadIdx.x;
  int Lb = c_L[b];
  if (tid < DH) qh[tid] = qpool[h*DH + tid];
  __syncthreads();
  size_t hb = (size_t)c_off[b]*DIM + h*DH;
  for (int k = tid; k < Lb; k += 256) {
    const float4* kp = (const float4*)(Kb + hb + (size_t)k*DIM);
    float a = 0.f;
    #pragma unroll
    for (int dd=0; dd<16; ++dd) {
      float4 kv = kp[dd];
      a += kv.x*qh[dd*4] + kv.y*qh[dd*4+1] + kv.z*qh[dd*4+2] + kv.w*qh[dd*4+3];
    }
    ss[k] = a*0.125f;
  }
  __syncthreads();
  float mx = -1e30f;
  for (int k=tid;k<Lb;k+=256) mx = fmaxf(mx, ss[k]);
  #pragma unroll
  for (int off=32; off; off>>=1) mx = fmaxf(mx, __shfl_xor(mx,off));
  if ((tid&63)==0) red[tid>>6] = mx;
  __syncthreads();
  mx = fmaxf(fmaxf(red[0],red[1]), fmaxf(red[2],red[3]));
  __syncthreads();
  float sum = 0.f;
  for (int k=tid;k<Lb;k+=256) { float p = __expf(ss[k]-mx); ss[k]=p; sum += p; }
  #pragma unroll
  for (int off=32; off; off>>=1) sum += __shfl_xor(sum,off);
  if ((tid&63)==0) red[tid>>6] = sum;
  __syncthreads();
  sum = red[0]+red[1]+red[2]+red[3];
  int d = tid & 63, c = tid >> 6;
  float a = 0.f;
  int kend = min(c*256+256, Lb);
  const float* vb = Vb + hb + d;
  for (int k = c*256; k < kend; ++k) a += ss[k]*vb[(size_t)k*DIM];
  part[c][d] = a;
  __syncthreads();
  if (tid < DH)
    O[(size_t)b*DIM + h*DH + tid] = (part[0][tid]+part[1][tid]+part[2][tid]+part[3][tid]) / sum;
}

// ---- tiny projection Y[8,512] = X[8,512] @ W[512,512]^T ----
__global__ __launch_bounds__(256) void proj512_k(
    const float* __restrict__ X, const float* __restrict__ W, float* __restrict__ Y) {
  __shared__ float xr[DIM];
  int b = blockIdx.x, tid = threadIdx.x;
  for (int i=tid;i<DIM;i+=256) xr[i] = X[(size_t)b*DIM+i];
  __syncthreads();
  for (int n=tid;n<DIM;n+=256) {
    const float4* wr = (const float4*)(W + (size_t)n*DIM);
    float a=0.f;
    for (int k=0;k<DIM/4;++k) { float4 w4 = wr[k]; a += w4.x*xr[k*4]+w4.y*xr[k*4+1]+w4.z*xr[k*4+2]+w4.w*xr[k*4+3]; }
    Y[(size_t)b*DIM+n]=a;
  }
}

// ---- final LN + classifier head ----
__global__ __launch_bounds__(256) void head_out_k(
    const float* __restrict__ X, const float* __restrict__ g,
    const float* __restrict__ W, float* __restrict__ out) {
  __shared__ float xr[DIM];
  __shared__ float red[8];
  int b = blockIdx.x, tid = threadIdx.x;
  float s=0.f, s2=0.f;
  for (int i=tid;i<DIM;i+=256){ float v=X[(size_t)b*DIM+i]; s+=v; s2+=v*v; }
  reduce2_256(s, s2, red);
  float mu=s*(1.f/DIM), rs=rsqrtf(fmaxf(s2*(1.f/DIM)-mu*mu,0.f)+1e-5f);
  for (int i=tid;i<DIM;i+=256) xr[i]=(X[(size_t)b*DIM+i]-mu)*rs*g[i];
  __syncthreads();
  for (int n=tid;n<NC;n+=256) {
    const float4* wr = (const float4*)(W + (size_t)n*DIM);
    float a=0.f;
    for (int k=0;k<DIM/4;++k){ float4 w4=wr[k]; a += w4.x*xr[k*4]+w4.y*xr[k*4+1]+w4.z*xr[k*4+2]+w4.w*xr[k*4+3]; }
    out[(size_t)b*NC+n]=a;
  }
}

extern "C" void kernel_launch(void* const* d_in, const int* in_sizes, int n_in,
                              void* d_out, int out_size, void* d_ws, size_t ws_size,
                              hipStream_t stream) {
  const float* images  = (const float*)d_in[0];
  const float* pe_ln1_w= (const float*)d_in[1];
  const float* pe_ln1_b= (const float*)d_in[2];
  const float* pe_w    = (const float*)d_in[3];
  const float* pe_b    = (const float*)d_in[4];
  const float* pe_ln2_w= (const float*)d_in[5];
  const float* pe_ln2_b= (const float*)d_in[6];
  const float* pos_h   = (const float*)d_in[7];
  const float* pos_w   = (const float*)d_in[8];
  const float* attn_ln = (const float*)d_in[9];
  const float* wq      = (const float*)d_in[10];
  const float* wk      = (const float*)d_in[11];
  const float* wvp     = (const float*)d_in[12];
  const float* qn      = (const float*)d_in[13];
  const float* kn      = (const float*)d_in[14];
  const float* wo      = (const float*)d_in[15];
  const float* ff_ln   = (const float*)d_in[16];
  const float* ff_w1   = (const float*)d_in[17];
  const float* ff_b1   = (const float*)d_in[18];
  const float* ff_w2   = (const float*)d_in[19];
  const float* ff_b2   = (const float*)d_in[20];
  const float* final_ln= (const float*)d_in[21];
  const float* pool_q  = (const float*)d_in[22];
  const float* pool_ln = (const float*)d_in[23];
  const float* pool_wq = (const float*)d_in[24];
  const float* pool_wk = (const float*)d_in[25];
  const float* pool_wv = (const float*)d_in[26];
  const float* pool_qn = (const float*)d_in[27];
  const float* pool_kn = (const float*)d_in[28];
  const float* pool_wo = (const float*)d_in[29];
  const float* head_ln = (const float*)d_in[30];
  const float* head_w  = (const float*)d_in[31];

  const size_t M = MPACK;
  float* ws = (float*)d_ws;
  float* FFH   = ws;                        // M*2048; aliases TOK and ATTO
  float* TOK   = ws;
  float* ATTO  = ws;
  float* T     = ws + M*MLP;
  float* XN    = T    + M*DIM;
  float* Qb    = XN   + M*DIM;
  float* Kbuf  = Qb   + M*DIM;
  float* Vbuf  = Kbuf + M*DIM;
  ushort* Qh   = (ushort*)(Vbuf + M*DIM);   // 64*1024*64 bf16 = 8MB
  ushort* Kh   = Qh + (size_t)64*LMAXS*DH;
  ushort* Vh   = Kh + (size_t)64*LMAXS*DH;
  float* QPOOL = (float*)(Vh + (size_t)64*LMAXS*DH);
  float* POOLO = QPOOL + DIM;
  float* POOLED= POOLO + NB*DIM;
  (void)ws_size; (void)in_sizes; (void)n_in; (void)out_size;

  // ---- patch embed (packed) ----
  pack_ln1_k<<<MPACK, 256, 0, stream>>>(images, pe_ln1_w, pe_ln1_b, TOK);
  gemm_nt<0,0><<<dim3(DIM/128, MPACK/128), 256, 0, stream>>>(TOK, pe_w, pe_b, T, MPACK, DIM, PDIM);
  ln2_pos_k<<<MPACK, 256, 0, stream>>>(T, pe_ln2_w, pe_ln2_b, pos_h, pos_w);

  // ---- transformer layers ----
  for (int l = 0; l < DEPTH; ++l) {
    row_ln_k<<<MPACK, 256, 0, stream>>>(T, attn_ln + l*DIM, XN, DIM);
    gemm_nt<0,0><<<dim3(4, MPACK/128), 256, 0, stream>>>(XN, wq  + (size_t)l*DIM*DIM, nullptr, Qb,   MPACK, DIM, DIM);
    gemm_nt<0,0><<<dim3(4, MPACK/128), 256, 0, stream>>>(XN, wk  + (size_t)l*DIM*DIM, nullptr, Kbuf, MPACK, DIM, DIM);
    gemm_nt<0,0><<<dim3(4, MPACK/128), 256, 0, stream>>>(XN, wvp + (size_t)l*DIM*DIM, nullptr, Vbuf, MPACK, DIM, DIM);
    split_ln_k<<<MVALID, 512, 0, stream>>>(Qb, Kbuf, Vbuf, qn + l*DH, kn + l*DH, Qh, Kh, Vh);
    attn_mfma_k<<<dim3(64, 16), 256, 0, stream>>>(Qh, Kh, Vh, ATTO);
    gemm_nt<0,1><<<dim3(4, MPACK/128), 256, 0, stream>>>(ATTO, wo + (size_t)l*DIM*DIM, nullptr, T, MPACK, DIM, DIM);
    row_ln_k<<<MPACK, 256, 0, stream>>>(T, ff_ln + l*DIM, XN, DIM);
    gemm_nt<1,0><<<dim3(MLP/128, MPACK/128), 256, 0, stream>>>(XN, ff_w1 + (size_t)l*MLP*DIM, ff_b1 + l*MLP, FFH, MPACK, MLP, DIM);
    gemm_nt<0,1><<<dim3(4, MPACK/128), 256, 0, stream>>>(FFH, ff_w2 + (size_t)l*DIM*MLP, ff_b2 + l*DIM, T, MPACK, DIM, MLP);
  }

  // ---- pooling head ----
  row_ln_k<<<MPACK, 256, 0, stream>>>(T, final_ln, XN, DIM);
  pool_prep_k<<<1, 256, 0, stream>>>(pool_q, pool_ln, pool_wq, pool_qn, QPOOL);
  gemm_nt<0,0><<<dim3(4, MPACK/128), 256, 0, stream>>>(XN, pool_wk, nullptr, Kbuf, MPACK, DIM, DIM);
  gemm_nt<0,0><<<dim3(4, MPACK/128), 256, 0, stream>>>(XN, pool_wv, nullptr, Vbuf, MPACK, DIM, DIM);
  head_ln_k<<<MPACK*HEADS/4, 256, 0, stream>>>(Kbuf, pool_kn);
  pool_attn_k<<<NB*HEADS, 256, 0, stream>>>(QPOOL, Kbuf, Vbuf, POOLO);
  proj512_k<<<NB, 256, 0, stream>>>(POOLO, pool_wo, POOLED);
  head_out_k<<<NB, 256, 0, stream>>>(POOLED, head_ln, head_w, (float*)d_out);
}

// Round 4
// 1869.701 us; speedup vs baseline: 3.0660x; 3.0660x over previous
//
#include <hip/hip_runtime.h>
#include <math.h>

#define LMAXS 1024
#define NB 8
#define DIM 512
#define HEADS 8
#define DH 64
#define DEPTH 6
#define MLP 2048
#define NC 1000
#define PDIM 768
#define MPACK 5376   // 5360 valid rows padded to 42*128
#define MVALID 5360

typedef __attribute__((ext_vector_type(8))) short short8;
typedef __attribute__((ext_vector_type(4))) float floatx4;
typedef unsigned short ushort;

// per-image patch grid width, valid token count L, packed row offset
__constant__ int c_w[8]   = {32,24,32,24,28,32,16,20};
__constant__ int c_L[8]   = {1024,768,896,576,560,512,384,640};
__constant__ int c_off[9] = {0,1024,1792,2688,3264,3824,4336,4720,5360};

__device__ __forceinline__ int row2img(int r) {
  int b = 0;
  #pragma unroll
  for (int i = 1; i < 8; ++i) if (r >= c_off[i]) b = i;
  return b;
}

__device__ __forceinline__ ushort f2bf(float x) {
  unsigned int u = __float_as_uint(x);
  u += 0x7fff + ((u >> 16) & 1);          // RNE
  return (ushort)(u >> 16);
}

// async global->LDS, 16B per lane; LDS dest must be wave-uniform base + lane*16
#define GLOAD_LDS16(gp, lp) \
  __builtin_amdgcn_global_load_lds((const __attribute__((address_space(1))) void*)(gp), \
                                   (__attribute__((address_space(3))) void*)(lp), 16, 0, 0)

// ---- block-wide (256 thr) sum + sumsq reduction ----
__device__ __forceinline__ void reduce2_256(float& s, float& s2, float* red) {
  #pragma unroll
  for (int off = 32; off; off >>= 1) {
    s  += __shfl_xor(s, off);
    s2 += __shfl_xor(s2, off);
  }
  int wv = threadIdx.x >> 6;
  if ((threadIdx.x & 63) == 0) { red[wv*2] = s; red[wv*2+1] = s2; }
  __syncthreads();
  s  = red[0] + red[2] + red[4] + red[6];
  s2 = red[1] + red[3] + red[5] + red[7];
  __syncthreads();
}

// ---- weight conversion fp32 -> bf16 ----
__global__ __launch_bounds__(256) void cvt_k(const float* __restrict__ s, ushort* __restrict__ d, int n) {
  int i = blockIdx.x*256 + threadIdx.x;
  if (i < n) d[i] = f2bf(s[i]);
}
// interleave wq/wk/wv -> [6][1536][512]
__global__ __launch_bounds__(256) void cvt_qkv_k(
    const float* __restrict__ wq, const float* __restrict__ wk, const float* __restrict__ wv,
    ushort* __restrict__ d) {
  int i = blockIdx.x*256 + threadIdx.x;
  if (i >= 6*1536*512) return;
  int l = i / (1536*512), r = (i / 512) % 1536, k = i & 511;
  const float* src = (r < 512) ? wq : (r < 1024) ? wk : wv;
  int rr = r & 511;
  d[i] = f2bf(src[(size_t)l*DIM*DIM + (size_t)rr*DIM + k]);
}
// stack pool_wk/pool_wv -> [1024][512]
__global__ __launch_bounds__(256) void cvt_pool_k(
    const float* __restrict__ wk, const float* __restrict__ wv, ushort* __restrict__ d) {
  int i = blockIdx.x*256 + threadIdx.x;
  if (i >= 1024*512) return;
  int r = i >> 9, k = i & 511;
  d[i] = f2bf(r < 512 ? wk[(size_t)r*DIM + k] : wv[(size_t)(r-512)*DIM + k]);
}

// ---- patchify + LN(768) -> bf16 packed tokens ----
__global__ __launch_bounds__(256) void pack_ln1_k(
    const float* __restrict__ images, const float* __restrict__ g,
    const float* __restrict__ bb, ushort* __restrict__ tok) {
  int r = blockIdx.x;
  ushort* out = tok + (size_t)r * PDIM;
  if (r >= MVALID) {
    for (int i = threadIdx.x; i < PDIM; i += 256) out[i] = 0;
    return;
  }
  int b = row2img(r), l = r - c_off[b];
  int wgrid = c_w[b];
  __shared__ float vals[PDIM];
  __shared__ float red[8];
  int hp = l / wgrid, wp = l % wgrid;
  const float* base = images + (size_t)b*3*512*512 + (size_t)hp*16*512 + wp*16;
  float s = 0.f, s2 = 0.f;
  for (int i = threadIdx.x; i < PDIM; i += 256) {
    int c = i >> 8, rr = (i >> 4) & 15, cc = i & 15;
    float v = base[(size_t)c*512*512 + rr*512 + cc];
    vals[i] = v; s += v; s2 += v*v;
  }
  reduce2_256(s, s2, red);
  float mu = s * (1.f/PDIM);
  float rs = rsqrtf(fmaxf(s2*(1.f/PDIM) - mu*mu, 0.f) + 1e-5f);
  for (int i = threadIdx.x; i < PDIM; i += 256)
    out[i] = f2bf((vals[i]-mu)*rs*g[i] + bb[i]);
}

// ---- bf16 MFMA GEMM: C[M,N] = act(A[M,K] @ W[N,K]^T + bias) ----
// 128x128 tile, BK=32, 256 thr = 4 waves in 2x2, each wave 64x64 (4x4 of 16x16 MFMA).
// OUT: 0 = f32 store, 1 = f32 accumulate, 2 = bf16 store. ACT: 1 = exact gelu.
template<int ACT, int OUT>
__global__ __launch_bounds__(256) void gemm_bf(
    const ushort* __restrict__ A, const ushort* __restrict__ W,
    const float* __restrict__ bias, void* __restrict__ Cv,
    int M, int N, int K) {
  __shared__ ushort As[128*32];
  __shared__ ushort Ws[128*32];
  int tid = threadIdx.x;
  int row0 = blockIdx.y*128, col0 = blockIdx.x*128;
  int lane = tid & 63, l15 = lane & 15, quad = lane >> 4;
  int wv = tid >> 6, wm = wv >> 1, wn = wv & 1;
  int c0 = tid, c1 = tid + 256;
  const ushort* Ag0 = A + (size_t)(row0 + (c0>>2))*K + (c0&3)*8;
  const ushort* Ag1 = A + (size_t)(row0 + (c1>>2))*K + (c1&3)*8;
  const ushort* Wg0 = W + (size_t)(col0 + (c0>>2))*K + (c0&3)*8;
  const ushort* Wg1 = W + (size_t)(col0 + (c1>>2))*K + (c1&3)*8;
  floatx4 acc[4][4] = {};
  for (int k0 = 0; k0 < K; k0 += 32) {
    __syncthreads();
    GLOAD_LDS16(Ag0 + k0, &As[c0*8]);
    GLOAD_LDS16(Ag1 + k0, &As[c1*8]);
    GLOAD_LDS16(Wg0 + k0, &Ws[c0*8]);
    GLOAD_LDS16(Wg1 + k0, &Ws[c1*8]);
    __syncthreads();
    short8 af[4], bf[4];
    #pragma unroll
    for (int i = 0; i < 4; ++i) af[i] = *(const short8*)&As[(wm*64 + i*16 + l15)*32 + quad*8];
    #pragma unroll
    for (int j = 0; j < 4; ++j) bf[j] = *(const short8*)&Ws[(wn*64 + j*16 + l15)*32 + quad*8];
    #pragma unroll
    for (int i = 0; i < 4; ++i)
      #pragma unroll
      for (int j = 0; j < 4; ++j)
        acc[i][j] = __builtin_amdgcn_mfma_f32_16x16x32_bf16(af[i], bf[j], acc[i][j], 0, 0, 0);
  }
  int rb = row0 + wm*64 + quad*4;
  int cb = col0 + wn*64 + l15;
  #pragma unroll
  for (int j = 0; j < 4; ++j) {
    int cc = cb + j*16;
    float bsum = bias ? bias[cc] : 0.f;
    #pragma unroll
    for (int i = 0; i < 4; ++i) {
      int rr = rb + i*16;
      #pragma unroll
      for (int reg = 0; reg < 4; ++reg) {
        float v = acc[i][j][reg] + bsum;
        if (ACT == 1) v = 0.5f*v*(1.f + erff(v*0.70710678118654752f));
        size_t idx = (size_t)(rr + reg)*N + cc;
        if (OUT == 0)      ((float*)Cv)[idx] = v;
        else if (OUT == 1) ((float*)Cv)[idx] += v;
        else               ((ushort*)Cv)[idx] = f2bf(v);
      }
    }
  }
}

// ---- row LayerNorm (width n), fp32 X -> bf16 Y ----
__global__ __launch_bounds__(256) void row_ln_bf_k(
    const float* __restrict__ X, const float* __restrict__ g,
    ushort* __restrict__ Y, int n) {
  __shared__ float red[8];
  size_t base = (size_t)blockIdx.x * n;
  float s=0.f, s2=0.f;
  for (int i = threadIdx.x; i < n; i += 256) { float v = X[base+i]; s += v; s2 += v*v; }
  reduce2_256(s, s2, red);
  float mu = s/n, rs = rsqrtf(fmaxf(s2/n - mu*mu, 0.f) + 1e-5f);
  for (int i = threadIdx.x; i < n; i += 256)
    Y[base+i] = f2bf((X[base+i]-mu)*rs*g[i]);
}

// ---- LN2 + bias + pos embed, packed, in place on fp32 T ----
__global__ __launch_bounds__(256) void ln2_pos_k(
    float* __restrict__ T, const float* __restrict__ g, const float* __restrict__ bb,
    const float* __restrict__ ph, const float* __restrict__ pw) {
  int r = blockIdx.x;
  float* x = T + (size_t)r * DIM;
  if (r >= MVALID) {
    for (int i = threadIdx.x; i < DIM; i += 256) x[i] = 0.f;
    return;
  }
  int b = row2img(r), l = r - c_off[b];
  __shared__ float red[8];
  int wgrid = c_w[b];
  int hi = l / wgrid, wi = l % wgrid;
  float s=0.f, s2=0.f;
  for (int i = threadIdx.x; i < DIM; i += 256) { float v = x[i]; s+=v; s2+=v*v; }
  reduce2_256(s, s2, red);
  float mu = s*(1.f/DIM), rs = rsqrtf(fmaxf(s2*(1.f/DIM)-mu*mu, 0.f)+1e-5f);
  for (int i = threadIdx.x; i < DIM; i += 256)
    x[i] = (x[i]-mu)*rs*g[i] + bb[i] + ph[hi*DIM+i] + pw[wi*DIM+i];
}

// ---- QKV split (from fused [r][1536] fp32) to per-head bf16 [b,h,l,64] + head-LN ----
__global__ __launch_bounds__(512) void split_ln_k(
    const float* __restrict__ QKV,
    const float* __restrict__ qn, const float* __restrict__ kn,
    ushort* __restrict__ Qh, ushort* __restrict__ Kh, ushort* __restrict__ Vh) {
  int r = blockIdx.x;                  // 0..MVALID-1
  int h = threadIdx.x >> 6, lane = threadIdx.x & 63;
  int b = row2img(r), l = r - c_off[b];
  size_t src = (size_t)r*1536 + h*DH + lane;
  size_t dst = ((size_t)(b*8+h)*LMAXS + l)*DH + lane;
  float v, s, s2, mu, rs;

  v = QKV[src]; s = v; s2 = v*v;
  #pragma unroll
  for (int off=32; off; off>>=1) { s += __shfl_xor(s,off); s2 += __shfl_xor(s2,off); }
  mu = s*(1.f/DH); rs = rsqrtf(fmaxf(s2*(1.f/DH)-mu*mu,0.f)+1e-5f);
  Qh[dst] = f2bf((v-mu)*rs*qn[lane]);

  v = QKV[src + 512]; s = v; s2 = v*v;
  #pragma unroll
  for (int off=32; off; off>>=1) { s += __shfl_xor(s,off); s2 += __shfl_xor(s2,off); }
  mu = s*(1.f/DH); rs = rsqrtf(fmaxf(s2*(1.f/DH)-mu*mu,0.f)+1e-5f);
  Kh[dst] = f2bf((v-mu)*rs*kn[lane]);

  Vh[dst] = f2bf(QKV[src + 1024]);
}

// ---- bf16 MFMA flash attention (output bf16) ----
__global__ __launch_bounds__(256) void attn_mfma_k(
    const ushort* __restrict__ Qh, const ushort* __restrict__ Kh,
    const ushort* __restrict__ Vh, ushort* __restrict__ O) {
  int bh = blockIdx.x, b = bh >> 3, h = bh & 7;
  int Lb = c_L[b];
  int qt = blockIdx.y;
  if (qt * 64 >= Lb) return;
  __shared__ ushort Ks[64][72];
  __shared__ ushort Vt[64][72];
  __shared__ ushort Pb[4][16][72];
  int tid = threadIdx.x, wv = tid >> 6, lane = tid & 63;
  int quad = lane >> 4, l15 = lane & 15;
  int q0 = qt*64 + wv*16;
  bool active = q0 < Lb;
  const ushort* qhb = Qh + (size_t)bh * LMAXS * DH;
  const ushort* khb = Kh + (size_t)bh * LMAXS * DH;
  const ushort* vhb = Vh + (size_t)bh * LMAXS * DH;
  short8 aq0 = {}, aq1 = {};
  if (active) {
    const ushort* qp = qhb + (size_t)(q0 + l15) * DH;
    aq0 = *(const short8*)(qp + quad*8);
    aq1 = *(const short8*)(qp + 32 + quad*8);
  }
  float mrow[4] = {-1e30f,-1e30f,-1e30f,-1e30f};
  float lrow[4] = {0.f,0.f,0.f,0.f};
  floatx4 o[4] = {};
  int krow = tid >> 2, dcol = (tid & 3) * 16;
  for (int kc = 0; kc < Lb; kc += 64) {
    __syncthreads();
    const ushort* kr = khb + (size_t)(kc + krow) * DH + dcol;
    *(short8*)&Ks[krow][dcol]   = *(const short8*)kr;
    *(short8*)&Ks[krow][dcol+8] = *(const short8*)(kr + 8);
    const ushort* vr = vhb + (size_t)(kc + krow) * DH + dcol;
    short8 v0 = *(const short8*)vr;
    short8 v1 = *(const short8*)(vr + 8);
    #pragma unroll
    for (int j = 0; j < 8; ++j) Vt[dcol+j][krow]   = (ushort)v0[j];
    #pragma unroll
    for (int j = 0; j < 8; ++j) Vt[dcol+8+j][krow] = (ushort)v1[j];
    __syncthreads();
    if (!active) continue;
    floatx4 sv[4];
    #pragma unroll
    for (int kb = 0; kb < 4; ++kb) {
      floatx4 s = {};
      s = __builtin_amdgcn_mfma_f32_16x16x32_bf16(aq0, *(const short8*)&Ks[kb*16+l15][quad*8], s, 0,0,0);
      s = __builtin_amdgcn_mfma_f32_16x16x32_bf16(aq1, *(const short8*)&Ks[kb*16+l15][32+quad*8], s, 0,0,0);
      sv[kb] = s;
    }
    bool tail = (kc + 64 > Lb);
    float rmax[4] = {-1e30f,-1e30f,-1e30f,-1e30f};
    #pragma unroll
    for (int kb = 0; kb < 4; ++kb)
      #pragma unroll
      for (int reg = 0; reg < 4; ++reg) {
        float x = sv[kb][reg] * 0.125f;
        if (tail && (kc + kb*16 + l15 >= Lb)) x = -1e9f;
        sv[kb][reg] = x;
        rmax[reg] = fmaxf(rmax[reg], x);
      }
    #pragma unroll
    for (int reg = 0; reg < 4; ++reg) {
      #pragma unroll
      for (int off = 1; off < 16; off <<= 1) rmax[reg] = fmaxf(rmax[reg], __shfl_xor(rmax[reg], off));
    }
    float alpha[4], rsum[4] = {0.f,0.f,0.f,0.f};
    #pragma unroll
    for (int reg = 0; reg < 4; ++reg) {
      float mn = fmaxf(mrow[reg], rmax[reg]);
      alpha[reg] = __expf(mrow[reg] - mn);
      mrow[reg] = mn;
    }
    #pragma unroll
    for (int kb = 0; kb < 4; ++kb)
      #pragma unroll
      for (int reg = 0; reg < 4; ++reg) {
        float p = __expf(sv[kb][reg] - mrow[reg]);
        rsum[reg] += p;
        Pb[wv][quad*4+reg][kb*16+l15] = f2bf(p);
      }
    #pragma unroll
    for (int reg = 0; reg < 4; ++reg) {
      #pragma unroll
      for (int off = 1; off < 16; off <<= 1) rsum[reg] += __shfl_xor(rsum[reg], off);
      lrow[reg] = lrow[reg]*alpha[reg] + rsum[reg];
    }
    #pragma unroll
    for (int nb = 0; nb < 4; ++nb)
      #pragma unroll
      for (int reg = 0; reg < 4; ++reg) o[nb][reg] *= alpha[reg];
    short8 a0 = *(const short8*)&Pb[wv][l15][quad*8];
    short8 a1 = *(const short8*)&Pb[wv][l15][32+quad*8];
    #pragma unroll
    for (int nb = 0; nb < 4; ++nb) {
      o[nb] = __builtin_amdgcn_mfma_f32_16x16x32_bf16(a0, *(const short8*)&Vt[nb*16+l15][quad*8], o[nb], 0,0,0);
      o[nb] = __builtin_amdgcn_mfma_f32_16x16x32_bf16(a1, *(const short8*)&Vt[nb*16+l15][32+quad*8], o[nb], 0,0,0);
    }
  }
  if (active) {
    int rbase = c_off[b] + q0 + quad*4;
    #pragma unroll
    for (int nb = 0; nb < 4; ++nb)
      #pragma unroll
      for (int reg = 0; reg < 4; ++reg)
        O[(size_t)(rbase+reg)*DIM + h*DH + nb*16 + l15] = f2bf(o[nb][reg] / lrow[reg]);
  }
}

// ---- pool query: LN(pool_q) @ pool_wq^T then per-head LN ----
__global__ __launch_bounds__(256) void pool_prep_k(
    const float* __restrict__ pq, const float* __restrict__ pln,
    const float* __restrict__ pwq, const float* __restrict__ pqn,
    float* __restrict__ qout) {
  __shared__ float qln[DIM];
  __shared__ float qp[DIM];
  __shared__ float red[8];
  __shared__ float hstat[16];
  int tid = threadIdx.x;
  float s=0.f, s2=0.f;
  for (int i=tid;i<DIM;i+=256){ float v=pq[i]; s+=v; s2+=v*v; }
  reduce2_256(s, s2, red);
  float mu=s*(1.f/DIM), rs=rsqrtf(fmaxf(s2*(1.f/DIM)-mu*mu,0.f)+1e-5f);
  for (int i=tid;i<DIM;i+=256) qln[i]=(pq[i]-mu)*rs*pln[i];
  __syncthreads();
  for (int n=tid;n<DIM;n+=256) {
    const float4* wr = (const float4*)(pwq + (size_t)n*DIM);
    float a=0.f;
    for (int k=0;k<DIM/4;++k) {
      float4 w4 = wr[k];
      float4 q4 = *(const float4*)&qln[k*4];
      a += w4.x*q4.x + w4.y*q4.y + w4.z*q4.z + w4.w*q4.w;
    }
    qp[n]=a;
  }
  __syncthreads();
  if (tid < 8) {
    float hs=0.f, hs2=0.f;
    for (int i=0;i<64;++i){ float v=qp[tid*64+i]; hs+=v; hs2+=v*v; }
    float hmu=hs*(1.f/64), hv=hs2*(1.f/64)-hmu*hmu;
    hstat[tid*2]=hmu; hstat[tid*2+1]=rsqrtf(fmaxf(hv,0.f)+1e-5f);
  }
  __syncthreads();
  for (int i=tid;i<DIM;i+=256) {
    int hh=i>>6;
    qout[i]=(qp[i]-hstat[hh*2])*hstat[hh*2+1]*pqn[i&63];
  }
}

// ---- per-head LN on K half of pooled KV buffer [MPACK][1024] ----
__global__ __launch_bounds__(256) void pool_kln_k(float* __restrict__ X, const float* __restrict__ g) {
  int rh = blockIdx.x*4 + (threadIdx.x >> 6);
  int lane = threadIdx.x & 63;
  float* x = X + (size_t)(rh >> 3)*1024 + (rh & 7)*64;
  float v = x[lane];
  float s = v, s2 = v*v;
  #pragma unroll
  for (int off=32; off; off>>=1) { s += __shfl_xor(s,off); s2 += __shfl_xor(s2,off); }
  float mu = s*(1.f/DH), rs = rsqrtf(fmaxf(s2*(1.f/DH)-mu*mu, 0.f)+1e-5f);
  x[lane] = (v-mu)*rs*g[lane];
}

// ---- pooling cross-attention over packed KV [MPACK][1024] (K cols 0-511, V 512-1023) ----
__global__ __launch_bounds__(256) void pool_attn_k(
    const float* __restrict__ qpool, const float* __restrict__ KV,
    float* __restrict__ O) {
  __shared__ float ss[LMAXS];
  __shared__ float qh[DH];
  __shared__ float red[4];
  __shared__ float part[4][DH];
  int bh = blockIdx.x, b = bh>>3, h = bh&7;
  int tid = threadIdx.x;
  int Lb = c_L[b];
  if (tid < DH) qh[tid] = qpool[h*DH + tid];
  __syncthreads();
  size_t kb = (size_t)c_off[b]*1024 + h*DH;
  for (int k = tid; k < Lb; k += 256) {
    const float4* kp = (const float4*)(KV + kb + (size_t)k*1024);
    float a = 0.f;
    #pragma unroll
    for (int dd=0; dd<16; ++dd) {
      float4 kv = kp[dd];
      a += kv.x*qh[dd*4] + kv.y*qh[dd*4+1] + kv.z*qh[dd*4+2] + kv.w*qh[dd*4+3];
    }
    ss[k] = a*0.125f;
  }
  __syncthreads();
  float mx = -1e30f;
  for (int k=tid;k<Lb;k+=256) mx = fmaxf(mx, ss[k]);
  #pragma unroll
  for (int off=32; off; off>>=1) mx = fmaxf(mx, __shfl_xor(mx,off));
  if ((tid&63)==0) red[tid>>6] = mx;
  __syncthreads();
  mx = fmaxf(fmaxf(red[0],red[1]), fmaxf(red[2],red[3]));
  __syncthreads();
  float sum = 0.f;
  for (int k=tid;k<Lb;k+=256) { float p = __expf(ss[k]-mx); ss[k]=p; sum += p; }
  #pragma unroll
  for (int off=32; off; off>>=1) sum += __shfl_xor(sum,off);
  if ((tid&63)==0) red[tid>>6] = sum;
  __syncthreads();
  sum = red[0]+red[1]+red[2]+red[3];
  int d = tid & 63, c = tid >> 6;
  float a = 0.f;
  int kend = min(c*256+256, Lb);
  const float* vb = KV + kb + 512 + d;
  for (int k = c*256; k < kend; ++k) a += ss[k]*vb[(size_t)k*1024];
  part[c][d] = a;
  __syncthreads();
  if (tid < DH)
    O[(size_t)b*DIM + h*DH + tid] = (part[0][tid]+part[1][tid]+part[2][tid]+part[3][tid]) / sum;
}

// ---- tiny projection Y[8,512] = X[8,512] @ W[512,512]^T ----
__global__ __launch_bounds__(256) void proj512_k(
    const float* __restrict__ X, const float* __restrict__ W, float* __restrict__ Y) {
  __shared__ float xr[DIM];
  int b = blockIdx.x, tid = threadIdx.x;
  for (int i=tid;i<DIM;i+=256) xr[i] = X[(size_t)b*DIM+i];
  __syncthreads();
  for (int n=tid;n<DIM;n+=256) {
    const float4* wr = (const float4*)(W + (size_t)n*DIM);
    float a=0.f;
    for (int k=0;k<DIM/4;++k) { float4 w4 = wr[k]; a += w4.x*xr[k*4]+w4.y*xr[k*4+1]+w4.z*xr[k*4+2]+w4.w*xr[k*4+3]; }
    Y[(size_t)b*DIM+n]=a;
  }
}

// ---- final LN + classifier head ----
__global__ __launch_bounds__(256) void head_out_k(
    const float* __restrict__ X, const float* __restrict__ g,
    const float* __restrict__ W, float* __restrict__ out) {
  __shared__ float xr[DIM];
  __shared__ float red[8];
  int b = blockIdx.x, tid = threadIdx.x;
  float s=0.f, s2=0.f;
  for (int i=tid;i<DIM;i+=256){ float v=X[(size_t)b*DIM+i]; s+=v; s2+=v*v; }
  reduce2_256(s, s2, red);
  float mu=s*(1.f/DIM), rs=rsqrtf(fmaxf(s2*(1.f/DIM)-mu*mu,0.f)+1e-5f);
  for (int i=tid;i<DIM;i+=256) xr[i]=(X[(size_t)b*DIM+i]-mu)*rs*g[i];
  __syncthreads();
  for (int n=tid;n<NC;n+=256) {
    const float4* wr = (const float4*)(W + (size_t)n*DIM);
    float a=0.f;
    for (int k=0;k<DIM/4;++k){ float4 w4=wr[k]; a += w4.x*xr[k*4]+w4.y*xr[k*4+1]+w4.z*xr[k*4+2]+w4.w*xr[k*4+3]; }
    out[(size_t)b*NC+n]=a;
  }
}

extern "C" void kernel_launch(void* const* d_in, const int* in_sizes, int n_in,
                              void* d_out, int out_size, void* d_ws, size_t ws_size,
                              hipStream_t stream) {
  const float* images  = (const float*)d_in[0];
  const float* pe_ln1_w= (const float*)d_in[1];
  const float* pe_ln1_b= (const float*)d_in[2];
  const float* pe_w    = (const float*)d_in[3];
  const float* pe_b    = (const float*)d_in[4];
  const float* pe_ln2_w= (const float*)d_in[5];
  const float* pe_ln2_b= (const float*)d_in[6];
  const float* pos_h   = (const float*)d_in[7];
  const float* pos_w   = (const float*)d_in[8];
  const float* attn_ln = (const float*)d_in[9];
  const float* wq      = (const float*)d_in[10];
  const float* wk      = (const float*)d_in[11];
  const float* wvp     = (const float*)d_in[12];
  const float* qn      = (const float*)d_in[13];
  const float* kn      = (const float*)d_in[14];
  const float* wo      = (const float*)d_in[15];
  const float* ff_ln   = (const float*)d_in[16];
  const float* ff_w1   = (const float*)d_in[17];
  const float* ff_b1   = (const float*)d_in[18];
  const float* ff_w2   = (const float*)d_in[19];
  const float* ff_b2   = (const float*)d_in[20];
  const float* final_ln= (const float*)d_in[21];
  const float* pool_q  = (const float*)d_in[22];
  const float* pool_ln = (const float*)d_in[23];
  const float* pool_wq = (const float*)d_in[24];
  const float* pool_wk = (const float*)d_in[25];
  const float* pool_wv = (const float*)d_in[26];
  const float* pool_qn = (const float*)d_in[27];
  const float* pool_kn = (const float*)d_in[28];
  const float* pool_wo = (const float*)d_in[29];
  const float* head_ln = (const float*)d_in[30];
  const float* head_w  = (const float*)d_in[31];
  (void)ws_size; (void)in_sizes; (void)n_in; (void)out_size;

  char* p = (char*)d_ws;
  ushort* WQKVc = (ushort*)p; p += (size_t)6*1536*512*2;   // 9.44 MB
  ushort* WOc   = (ushort*)p; p += (size_t)6*512*512*2;    // 3.15 MB
  ushort* W1c   = (ushort*)p; p += (size_t)6*2048*512*2;   // 12.6 MB
  ushort* W2c   = (ushort*)p; p += (size_t)6*512*2048*2;   // 12.6 MB
  ushort* PEWc  = (ushort*)p; p += (size_t)512*768*2;      // 0.79 MB
  ushort* PKVc  = (ushort*)p; p += (size_t)1024*512*2;     // 1.05 MB
  float*  T     = (float*)p;  p += (size_t)MPACK*DIM*4;    // 11.0 MB
  ushort* XN    = (ushort*)p; p += (size_t)MPACK*DIM*2;    // 5.5 MB
  float*  QKVb  = (float*)p;  p += (size_t)MPACK*1536*4;   // 33.0 MB (pool KV [MPACK][1024] aliases)
  ushort* Qh    = (ushort*)p; p += (size_t)64*LMAXS*DH*2;  // 8.4 MB
  ushort* Kh    = (ushort*)p; p += (size_t)64*LMAXS*DH*2;
  ushort* Vh    = (ushort*)p; p += (size_t)64*LMAXS*DH*2;
  ushort* FFH   = (ushort*)p; p += (size_t)MPACK*MLP*2;    // 22.0 MB (aliases TOK, ATTO)
  ushort* TOK   = FFH;
  ushort* ATTO  = FFH;
  float*  QPOOL = (float*)p;  p += DIM*4;
  float*  POOLO = (float*)p;  p += NB*DIM*4;
  float*  POOLED= (float*)p;  p += NB*DIM*4;

  // ---- weight conversion (every call; same work each launch) ----
  cvt_qkv_k<<<(6*1536*512+255)/256, 256, 0, stream>>>(wq, wk, wvp, WQKVc);
  cvt_k<<<(6*512*512+255)/256, 256, 0, stream>>>(wo, WOc, 6*512*512);
  cvt_k<<<(6*2048*512+255)/256, 256, 0, stream>>>(ff_w1, W1c, 6*2048*512);
  cvt_k<<<(6*512*2048+255)/256, 256, 0, stream>>>(ff_w2, W2c, 6*512*2048);
  cvt_k<<<(512*768+255)/256, 256, 0, stream>>>(pe_w, PEWc, 512*768);
  cvt_pool_k<<<(1024*512+255)/256, 256, 0, stream>>>(pool_wk, pool_wv, PKVc);

  // ---- patch embed (packed) ----
  pack_ln1_k<<<MPACK, 256, 0, stream>>>(images, pe_ln1_w, pe_ln1_b, TOK);
  gemm_bf<0,0><<<dim3(4, MPACK/128), 256, 0, stream>>>(TOK, PEWc, pe_b, T, MPACK, DIM, PDIM);
  ln2_pos_k<<<MPACK, 256, 0, stream>>>(T, pe_ln2_w, pe_ln2_b, pos_h, pos_w);

  // ---- transformer layers ----
  for (int l = 0; l < DEPTH; ++l) {
    row_ln_bf_k<<<MPACK, 256, 0, stream>>>(T, attn_ln + l*DIM, XN, DIM);
    gemm_bf<0,0><<<dim3(12, MPACK/128), 256, 0, stream>>>(XN, WQKVc + (size_t)l*1536*512, nullptr, QKVb, MPACK, 1536, DIM);
    split_ln_k<<<MVALID, 512, 0, stream>>>(QKVb, qn + l*DH, kn + l*DH, Qh, Kh, Vh);
    attn_mfma_k<<<dim3(64, 16), 256, 0, stream>>>(Qh, Kh, Vh, ATTO);
    gemm_bf<0,1><<<dim3(4, MPACK/128), 256, 0, stream>>>(ATTO, WOc + (size_t)l*512*512, nullptr, T, MPACK, DIM, DIM);
    row_ln_bf_k<<<MPACK, 256, 0, stream>>>(T, ff_ln + l*DIM, XN, DIM);
    gemm_bf<1,2><<<dim3(16, MPACK/128), 256, 0, stream>>>(XN, W1c + (size_t)l*MLP*DIM, ff_b1 + l*MLP, FFH, MPACK, MLP, DIM);
    gemm_bf<0,1><<<dim3(4, MPACK/128), 256, 0, stream>>>(FFH, W2c + (size_t)l*DIM*MLP, ff_b2 + l*DIM, T, MPACK, DIM, MLP);
  }

  // ---- pooling head ----
  row_ln_bf_k<<<MPACK, 256, 0, stream>>>(T, final_ln, XN, DIM);
  pool_prep_k<<<1, 256, 0, stream>>>(pool_q, pool_ln, pool_wq, pool_qn, QPOOL);
  gemm_bf<0,0><<<dim3(8, MPACK/128), 256, 0, stream>>>(XN, PKVc, nullptr, QKVb, MPACK, 1024, DIM);
  pool_kln_k<<<MPACK*HEADS/4, 256, 0, stream>>>(QKVb, pool_kn);
  pool_attn_k<<<NB*HEADS, 256, 0, stream>>>(QPOOL, QKVb, POOLO);
  proj512_k<<<NB, 256, 0, stream>>>(POOLO, pool_wo, POOLED);
  head_out_k<<<NB, 256, 0, stream>>>(POOLED, head_ln, head_w, (float*)d_out);
}

// Round 5
// 1619.959 us; speedup vs baseline: 3.5387x; 1.1542x over previous
//
#include <hip/hip_runtime.h>
#include <math.h>

#define LMAXS 1024
#define NB 8
#define DIM 512
#define HEADS 8
#define DH 64
#define DEPTH 6
#define MLP 2048
#define NC 1000
#define PDIM 768
#define MPACK 5376   // 5360 valid rows padded to 42*128
#define MVALID 5360

typedef __attribute__((ext_vector_type(8))) short short8;
typedef __attribute__((ext_vector_type(4))) float floatx4;
typedef unsigned short ushort;

// per-image patch grid width, valid token count L, packed row offset
__constant__ int c_w[8]   = {32,24,32,24,28,32,16,20};
__constant__ int c_L[8]   = {1024,768,896,576,560,512,384,640};
__constant__ int c_off[9] = {0,1024,1792,2688,3264,3824,4336,4720,5360};

__device__ __forceinline__ int row2img(int r) {
  int b = 0;
  #pragma unroll
  for (int i = 1; i < 8; ++i) if (r >= c_off[i]) b = i;
  return b;
}

__device__ __forceinline__ ushort f2bf(float x) {
  unsigned int u = __float_as_uint(x);
  u += 0x7fff + ((u >> 16) & 1);          // RNE
  return (ushort)(u >> 16);
}

// async global->LDS, 16B per lane; LDS dest must be wave-uniform base + lane*16
#define GLOAD_LDS16(gp, lp) \
  __builtin_amdgcn_global_load_lds((const __attribute__((address_space(1))) void*)(gp), \
                                   (__attribute__((address_space(3))) void*)(lp), 16, 0, 0)

// ---- block-wide (256 thr) sum + sumsq reduction ----
__device__ __forceinline__ void reduce2_256(float& s, float& s2, float* red) {
  #pragma unroll
  for (int off = 32; off; off >>= 1) {
    s  += __shfl_xor(s, off);
    s2 += __shfl_xor(s2, off);
  }
  int wv = threadIdx.x >> 6;
  if ((threadIdx.x & 63) == 0) { red[wv*2] = s; red[wv*2+1] = s2; }
  __syncthreads();
  s  = red[0] + red[2] + red[4] + red[6];
  s2 = red[1] + red[3] + red[5] + red[7];
  __syncthreads();
}

// ---- weight conversion fp32 -> bf16 ----
__global__ __launch_bounds__(256) void cvt_k(const float* __restrict__ s, ushort* __restrict__ d, int n) {
  int i = blockIdx.x*256 + threadIdx.x;
  if (i < n) d[i] = f2bf(s[i]);
}
// interleave wq/wk/wv -> [6][1536][512]
__global__ __launch_bounds__(256) void cvt_qkv_k(
    const float* __restrict__ wq, const float* __restrict__ wk, const float* __restrict__ wv,
    ushort* __restrict__ d) {
  int i = blockIdx.x*256 + threadIdx.x;
  if (i >= 6*1536*512) return;
  int l = i / (1536*512), r = (i / 512) % 1536, k = i & 511;
  const float* src = (r < 512) ? wq : (r < 1024) ? wk : wv;
  int rr = r & 511;
  d[i] = f2bf(src[(size_t)l*DIM*DIM + (size_t)rr*DIM + k]);
}
// stack pool_wk/pool_wv -> [1024][512]
__global__ __launch_bounds__(256) void cvt_pool_k(
    const float* __restrict__ wk, const float* __restrict__ wv, ushort* __restrict__ d) {
  int i = blockIdx.x*256 + threadIdx.x;
  if (i >= 1024*512) return;
  int r = i >> 9, k = i & 511;
  d[i] = f2bf(r < 512 ? wk[(size_t)r*DIM + k] : wv[(size_t)(r-512)*DIM + k]);
}

// ---- patchify + LN(768) -> bf16 packed tokens ----
__global__ __launch_bounds__(256) void pack_ln1_k(
    const float* __restrict__ images, const float* __restrict__ g,
    const float* __restrict__ bb, ushort* __restrict__ tok) {
  int r = blockIdx.x;
  ushort* out = tok + (size_t)r * PDIM;
  if (r >= MVALID) {
    for (int i = threadIdx.x; i < PDIM; i += 256) out[i] = 0;
    return;
  }
  int b = row2img(r), l = r - c_off[b];
  int wgrid = c_w[b];
  __shared__ float vals[PDIM];
  __shared__ float red[8];
  int hp = l / wgrid, wp = l % wgrid;
  const float* base = images + (size_t)b*3*512*512 + (size_t)hp*16*512 + wp*16;
  float s = 0.f, s2 = 0.f;
  for (int i = threadIdx.x; i < PDIM; i += 256) {
    int c = i >> 8, rr = (i >> 4) & 15, cc = i & 15;
    float v = base[(size_t)c*512*512 + rr*512 + cc];
    vals[i] = v; s += v; s2 += v*v;
  }
  reduce2_256(s, s2, red);
  float mu = s * (1.f/PDIM);
  float rs = rsqrtf(fmaxf(s2*(1.f/PDIM) - mu*mu, 0.f) + 1e-5f);
  for (int i = threadIdx.x; i < PDIM; i += 256)
    out[i] = f2bf((vals[i]-mu)*rs*g[i] + bb[i]);
}

// ---- bf16 MFMA GEMM: C[M,N] = act(A[M,K] @ W[N,K]^T + bias) ----
// 128x128 tile, BK=32, 256 thr = 4 waves in 2x2, each wave 64x64 (4x4 of 16x16 MFMA).
// OUT: 0 = f32 store, 1 = f32 atomic-accumulate (supports split-K via gridDim.z), 2 = bf16 store.
template<int ACT, int OUT>
__global__ __launch_bounds__(256) void gemm_bf(
    const ushort* __restrict__ A, const ushort* __restrict__ W,
    const float* __restrict__ bias, void* __restrict__ Cv,
    int M, int N, int K) {
  __shared__ ushort As[128*32];
  __shared__ ushort Ws[128*32];
  int tid = threadIdx.x;
  int row0 = blockIdx.y*128, col0 = blockIdx.x*128;
  int lane = tid & 63, l15 = lane & 15, quad = lane >> 4;
  int wv = tid >> 6, wm = wv >> 1, wn = wv & 1;
  int c0 = tid, c1 = tid + 256;
  const ushort* Ag0 = A + (size_t)(row0 + (c0>>2))*K + (c0&3)*8;
  const ushort* Ag1 = A + (size_t)(row0 + (c1>>2))*K + (c1&3)*8;
  const ushort* Wg0 = W + (size_t)(col0 + (c0>>2))*K + (c0&3)*8;
  const ushort* Wg1 = W + (size_t)(col0 + (c1>>2))*K + (c1&3)*8;
  int ksl = K / gridDim.z;
  int kb0 = blockIdx.z * ksl;
  floatx4 acc[4][4] = {};
  for (int k0 = kb0; k0 < kb0 + ksl; k0 += 32) {
    __syncthreads();
    GLOAD_LDS16(Ag0 + k0, &As[c0*8]);
    GLOAD_LDS16(Ag1 + k0, &As[c1*8]);
    GLOAD_LDS16(Wg0 + k0, &Ws[c0*8]);
    GLOAD_LDS16(Wg1 + k0, &Ws[c1*8]);
    __syncthreads();
    short8 af[4], bf[4];
    #pragma unroll
    for (int i = 0; i < 4; ++i) af[i] = *(const short8*)&As[(wm*64 + i*16 + l15)*32 + quad*8];
    #pragma unroll
    for (int j = 0; j < 4; ++j) bf[j] = *(const short8*)&Ws[(wn*64 + j*16 + l15)*32 + quad*8];
    #pragma unroll
    for (int i = 0; i < 4; ++i)
      #pragma unroll
      for (int j = 0; j < 4; ++j)
        acc[i][j] = __builtin_amdgcn_mfma_f32_16x16x32_bf16(af[i], bf[j], acc[i][j], 0, 0, 0);
  }
  int rb = row0 + wm*64 + quad*4;
  int cb = col0 + wn*64 + l15;
  bool addb = (bias != nullptr) && (blockIdx.z == 0);
  #pragma unroll
  for (int j = 0; j < 4; ++j) {
    int cc = cb + j*16;
    float bsum = addb ? bias[cc] : 0.f;
    #pragma unroll
    for (int i = 0; i < 4; ++i) {
      int rr = rb + i*16;
      #pragma unroll
      for (int reg = 0; reg < 4; ++reg) {
        float v = acc[i][j][reg] + bsum;
        if (ACT == 1) v = 0.5f*v*(1.f + erff(v*0.70710678118654752f));
        size_t idx = (size_t)(rr + reg)*N + cc;
        if (OUT == 0)      ((float*)Cv)[idx] = v;
        else if (OUT == 1) unsafeAtomicAdd(&((float*)Cv)[idx], v);
        else               ((ushort*)Cv)[idx] = f2bf(v);
      }
    }
  }
}

// ---- QKV / pool-KV GEMM with fused per-head LN in epilogue ----
// POOL=0: N=1536, writes Qh/Kh/Vh bf16 [b,h,l,64] (LN on Q,K units).
// POOL=1: N=1024, writes KV fp32 [row][1024] (LN on K units = cols<512).
template<int POOL>
__global__ __launch_bounds__(256) void gemm_qkv_k(
    const ushort* __restrict__ A, const ushort* __restrict__ W,
    const float* __restrict__ gq, const float* __restrict__ gk,
    ushort* __restrict__ Qh, ushort* __restrict__ Kh, ushort* __restrict__ Vh,
    float* __restrict__ KV, int N) {
  const int K = DIM;
  __shared__ ushort As[128*32];
  __shared__ ushort Ws[128*32];
  int tid = threadIdx.x;
  int row0 = blockIdx.y*128, col0 = blockIdx.x*128;
  int lane = tid & 63, l15 = lane & 15, quad = lane >> 4;
  int wv = tid >> 6, wm = wv >> 1, wn = wv & 1;
  int c0 = tid, c1 = tid + 256;
  const ushort* Ag0 = A + (size_t)(row0 + (c0>>2))*K + (c0&3)*8;
  const ushort* Ag1 = A + (size_t)(row0 + (c1>>2))*K + (c1&3)*8;
  const ushort* Wg0 = W + (size_t)(col0 + (c0>>2))*K + (c0&3)*8;
  const ushort* Wg1 = W + (size_t)(col0 + (c1>>2))*K + (c1&3)*8;
  floatx4 acc[4][4] = {};
  for (int k0 = 0; k0 < K; k0 += 32) {
    __syncthreads();
    GLOAD_LDS16(Ag0 + k0, &As[c0*8]);
    GLOAD_LDS16(Ag1 + k0, &As[c1*8]);
    GLOAD_LDS16(Wg0 + k0, &Ws[c0*8]);
    GLOAD_LDS16(Wg1 + k0, &Ws[c1*8]);
    __syncthreads();
    short8 af[4], bf[4];
    #pragma unroll
    for (int i = 0; i < 4; ++i) af[i] = *(const short8*)&As[(wm*64 + i*16 + l15)*32 + quad*8];
    #pragma unroll
    for (int j = 0; j < 4; ++j) bf[j] = *(const short8*)&Ws[(wn*64 + j*16 + l15)*32 + quad*8];
    #pragma unroll
    for (int i = 0; i < 4; ++i)
      #pragma unroll
      for (int j = 0; j < 4; ++j)
        acc[i][j] = __builtin_amdgcn_mfma_f32_16x16x32_bf16(af[i], bf[j], acc[i][j], 0, 0, 0);
  }
  // epilogue: wave's 64-col span = exactly one head-unit
  int unit = (col0 >> 6) + wn;              // POOL=0: 0..23 (Q/K/V x head); POOL=1: 0..15 (K/V x head)
  bool needln = POOL ? (unit < 8) : (unit < 16);
  const float* gain = POOL ? gq : (unit < 8 ? gq : gk);
  #pragma unroll
  for (int i = 0; i < 4; ++i) {
    float s[4] = {0,0,0,0}, s2[4] = {0,0,0,0};
    if (needln) {
      #pragma unroll
      for (int j = 0; j < 4; ++j)
        #pragma unroll
        for (int reg = 0; reg < 4; ++reg) {
          float v = acc[i][j][reg];
          s[reg] += v; s2[reg] += v*v;
        }
      #pragma unroll
      for (int reg = 0; reg < 4; ++reg)
        #pragma unroll
        for (int off = 1; off < 16; off <<= 1) {
          s[reg]  += __shfl_xor(s[reg],  off);
          s2[reg] += __shfl_xor(s2[reg], off);
        }
    }
    #pragma unroll
    for (int reg = 0; reg < 4; ++reg) {
      int r = row0 + wm*64 + i*16 + quad*4 + reg;
      if (r >= MVALID) continue;
      float mu = s[reg]*(1.f/64.f);
      float rs = rsqrtf(fmaxf(s2[reg]*(1.f/64.f) - mu*mu, 0.f) + 1e-5f);
      int b = row2img(r), l = r - c_off[b];
      #pragma unroll
      for (int j = 0; j < 4; ++j) {
        int dh = j*16 + l15;
        float v = acc[i][j][reg];
        if (needln) v = (v - mu)*rs*gain[dh];
        if (POOL) {
          KV[(size_t)r*1024 + unit*64 + dh] = v;
        } else {
          int h = unit & 7;
          size_t dst = ((size_t)(b*8+h)*LMAXS + l)*64 + dh;
          if (unit < 8)       Qh[dst] = f2bf(v);
          else if (unit < 16) Kh[dst] = f2bf(v);
          else                Vh[dst] = f2bf(v);
        }
      }
    }
  }
}

// ---- row LayerNorm (width n), fp32 X -> bf16 Y ----
__global__ __launch_bounds__(256) void row_ln_bf_k(
    const float* __restrict__ X, const float* __restrict__ g,
    ushort* __restrict__ Y, int n) {
  __shared__ float red[8];
  size_t base = (size_t)blockIdx.x * n;
  float s=0.f, s2=0.f;
  for (int i = threadIdx.x; i < n; i += 256) { float v = X[base+i]; s += v; s2 += v*v; }
  reduce2_256(s, s2, red);
  float mu = s/n, rs = rsqrtf(fmaxf(s2/n - mu*mu, 0.f) + 1e-5f);
  for (int i = threadIdx.x; i < n; i += 256)
    Y[base+i] = f2bf((X[base+i]-mu)*rs*g[i]);
}

// ---- LN2 + bias + pos embed, packed, in place on fp32 T ----
__global__ __launch_bounds__(256) void ln2_pos_k(
    float* __restrict__ T, const float* __restrict__ g, const float* __restrict__ bb,
    const float* __restrict__ ph, const float* __restrict__ pw) {
  int r = blockIdx.x;
  float* x = T + (size_t)r * DIM;
  if (r >= MVALID) {
    for (int i = threadIdx.x; i < DIM; i += 256) x[i] = 0.f;
    return;
  }
  int b = row2img(r), l = r - c_off[b];
  __shared__ float red[8];
  int wgrid = c_w[b];
  int hi = l / wgrid, wi = l % wgrid;
  float s=0.f, s2=0.f;
  for (int i = threadIdx.x; i < DIM; i += 256) { float v = x[i]; s+=v; s2+=v*v; }
  reduce2_256(s, s2, red);
  float mu = s*(1.f/DIM), rs = rsqrtf(fmaxf(s2*(1.f/DIM)-mu*mu, 0.f)+1e-5f);
  for (int i = threadIdx.x; i < DIM; i += 256)
    x[i] = (x[i]-mu)*rs*g[i] + bb[i] + ph[hi*DIM+i] + pw[wi*DIM+i];
}

// ---- V transpose per head: Vh [bh][l][64] -> VhT [bh][64][LMAX] ----
__global__ __launch_bounds__(256) void vtrans_k(
    const ushort* __restrict__ Vh, ushort* __restrict__ VhT) {
  int bh = blockIdx.x, b = bh >> 3;
  int lt = blockIdx.y;
  if (lt*64 >= c_L[b]) return;
  __shared__ ushort t[64][72];
  int tid = threadIdx.x;
  int row = tid >> 2, seg = (tid & 3)*16;
  const ushort* src = Vh + ((size_t)bh*LMAXS + lt*64 + row)*64 + seg;
  *(short8*)&t[row][seg]   = *(const short8*)src;
  *(short8*)&t[row][seg+8] = *(const short8*)(src+8);
  __syncthreads();
  int dh = tid >> 2, ks = (tid & 3)*16;
  short8 o0, o1;
  #pragma unroll
  for (int jj = 0; jj < 8; ++jj) o0[jj] = (short)t[ks+jj][dh];
  #pragma unroll
  for (int jj = 0; jj < 8; ++jj) o1[jj] = (short)t[ks+8+jj][dh];
  ushort* dst = VhT + ((size_t)bh*64 + dh)*LMAXS + lt*64 + ks;
  *(short8*)dst     = o0;
  *(short8*)(dst+8) = o1;
}

// ---- bf16 MFMA flash attention (V pre-transposed; output bf16) ----
__global__ __launch_bounds__(256) void attn_mfma_k(
    const ushort* __restrict__ Qh, const ushort* __restrict__ Kh,
    const ushort* __restrict__ VhT, ushort* __restrict__ O) {
  int bh = blockIdx.x, b = bh >> 3, h = bh & 7;
  int Lb = c_L[b];
  int qt = blockIdx.y;
  if (qt * 64 >= Lb) return;
  __shared__ ushort Ks[64][72];
  __shared__ ushort Vt[64][72];
  __shared__ ushort Pb[4][16][72];
  int tid = threadIdx.x, wv = tid >> 6, lane = tid & 63;
  int quad = lane >> 4, l15 = lane & 15;
  int q0 = qt*64 + wv*16;
  bool active = q0 < Lb;
  const ushort* qhb = Qh + (size_t)bh * LMAXS * DH;
  const ushort* khb = Kh + (size_t)bh * LMAXS * DH;
  const ushort* vtb = VhT + (size_t)bh * 64 * LMAXS;
  short8 aq0 = {}, aq1 = {};
  if (active) {
    const ushort* qp = qhb + (size_t)(q0 + l15) * DH;
    aq0 = *(const short8*)(qp + quad*8);
    aq1 = *(const short8*)(qp + 32 + quad*8);
  }
  float mrow[4] = {-1e30f,-1e30f,-1e30f,-1e30f};
  float lrow[4] = {0.f,0.f,0.f,0.f};
  floatx4 o[4] = {};
  int srow = tid >> 2, sseg = (tid & 3) * 16;
  for (int kc = 0; kc < Lb; kc += 64) {
    __syncthreads();
    const ushort* kr = khb + (size_t)(kc + srow) * DH + sseg;
    *(short8*)&Ks[srow][sseg]   = *(const short8*)kr;
    *(short8*)&Ks[srow][sseg+8] = *(const short8*)(kr + 8);
    const ushort* vr = vtb + (size_t)srow * LMAXS + kc + sseg;
    *(short8*)&Vt[srow][sseg]   = *(const short8*)vr;
    *(short8*)&Vt[srow][sseg+8] = *(const short8*)(vr + 8);
    __syncthreads();
    if (!active) continue;
    floatx4 sv[4];
    #pragma unroll
    for (int kb = 0; kb < 4; ++kb) {
      floatx4 s = {};
      s = __builtin_amdgcn_mfma_f32_16x16x32_bf16(aq0, *(const short8*)&Ks[kb*16+l15][quad*8], s, 0,0,0);
      s = __builtin_amdgcn_mfma_f32_16x16x32_bf16(aq1, *(const short8*)&Ks[kb*16+l15][32+quad*8], s, 0,0,0);
      sv[kb] = s;
    }
    bool tail = (kc + 64 > Lb);
    float rmax[4] = {-1e30f,-1e30f,-1e30f,-1e30f};
    #pragma unroll
    for (int kb = 0; kb < 4; ++kb)
      #pragma unroll
      for (int reg = 0; reg < 4; ++reg) {
        float x = sv[kb][reg] * 0.125f;
        if (tail && (kc + kb*16 + l15 >= Lb)) x = -1e9f;
        sv[kb][reg] = x;
        rmax[reg] = fmaxf(rmax[reg], x);
      }
    #pragma unroll
    for (int reg = 0; reg < 4; ++reg) {
      #pragma unroll
      for (int off = 1; off < 16; off <<= 1) rmax[reg] = fmaxf(rmax[reg], __shfl_xor(rmax[reg], off));
    }
    float alpha[4], rsum[4] = {0.f,0.f,0.f,0.f};
    #pragma unroll
    for (int reg = 0; reg < 4; ++reg) {
      float mn = fmaxf(mrow[reg], rmax[reg]);
      alpha[reg] = __expf(mrow[reg] - mn);
      mrow[reg] = mn;
    }
    #pragma unroll
    for (int kb = 0; kb < 4; ++kb)
      #pragma unroll
      for (int reg = 0; reg < 4; ++reg) {
        float p = __expf(sv[kb][reg] - mrow[reg]);
        rsum[reg] += p;
        Pb[wv][quad*4+reg][kb*16+l15] = f2bf(p);
      }
    #pragma unroll
    for (int reg = 0; reg < 4; ++reg) {
      #pragma unroll
      for (int off = 1; off < 16; off <<= 1) rsum[reg] += __shfl_xor(rsum[reg], off);
      lrow[reg] = lrow[reg]*alpha[reg] + rsum[reg];
    }
    #pragma unroll
    for (int nb = 0; nb < 4; ++nb)
      #pragma unroll
      for (int reg = 0; reg < 4; ++reg) o[nb][reg] *= alpha[reg];
    short8 a0 = *(const short8*)&Pb[wv][l15][quad*8];
    short8 a1 = *(const short8*)&Pb[wv][l15][32+quad*8];
    #pragma unroll
    for (int nb = 0; nb < 4; ++nb) {
      o[nb] = __builtin_amdgcn_mfma_f32_16x16x32_bf16(a0, *(const short8*)&Vt[nb*16+l15][quad*8], o[nb], 0,0,0);
      o[nb] = __builtin_amdgcn_mfma_f32_16x16x32_bf16(a1, *(const short8*)&Vt[nb*16+l15][32+quad*8], o[nb], 0,0,0);
    }
  }
  if (active) {
    int rbase = c_off[b] + q0 + quad*4;
    #pragma unroll
    for (int nb = 0; nb < 4; ++nb)
      #pragma unroll
      for (int reg = 0; reg < 4; ++reg)
        O[(size_t)(rbase+reg)*DIM + h*DH + nb*16 + l15] = f2bf(o[nb][reg] / lrow[reg]);
  }
}

// ---- pool query prep A: qp = LN(pool_q) @ pool_wq^T, column-parallel ----
__global__ __launch_bounds__(256) void pool_prep_a_k(
    const float* __restrict__ pq, const float* __restrict__ pln,
    const float* __restrict__ pwq, float* __restrict__ qp) {
  __shared__ float qln[DIM];
  __shared__ float red[8];
  int tid = threadIdx.x;
  float s=0.f, s2=0.f;
  for (int i=tid;i<DIM;i+=256){ float v=pq[i]; s+=v; s2+=v*v; }
  reduce2_256(s, s2, red);
  float mu=s*(1.f/DIM), rs=rsqrtf(fmaxf(s2*(1.f/DIM)-mu*mu,0.f)+1e-5f);
  for (int i=tid;i<DIM;i+=256) qln[i]=(pq[i]-mu)*rs*pln[i];
  __syncthreads();
  int n = blockIdx.x*64 + (tid>>2);
  int kq = (tid&3)*128;
  const float4* wr = (const float4*)(pwq + (size_t)n*DIM + kq);
  float a=0.f;
  #pragma unroll
  for (int k=0;k<32;++k) {
    float4 w4 = wr[k];
    float4 q4 = *(const float4*)&qln[kq + k*4];
    a += w4.x*q4.x + w4.y*q4.y + w4.z*q4.z + w4.w*q4.w;
  }
  a += __shfl_xor(a,1); a += __shfl_xor(a,2);
  if ((tid&3)==0) qp[n]=a;
}

// ---- pool query prep B: per-head LN on qp -> qpool ----
__global__ __launch_bounds__(512) void pool_prep_b_k(
    const float* __restrict__ qp, const float* __restrict__ pqn, float* __restrict__ qpool) {
  int h = threadIdx.x >> 6, lane = threadIdx.x & 63;
  float v = qp[h*64 + lane];
  float s = v, s2 = v*v;
  #pragma unroll
  for (int off=32; off; off>>=1) { s += __shfl_xor(s,off); s2 += __shfl_xor(s2,off); }
  float mu = s*(1.f/64), rs = rsqrtf(fmaxf(s2*(1.f/64)-mu*mu, 0.f)+1e-5f);
  qpool[h*64+lane] = (v-mu)*rs*pqn[lane];
}

// ---- pooling cross-attention, phase 1: per (bh, key-chunk) partials ----
// scores bounded (|q|=|k|=8 after unit-gain LN => |s|<=8), so exp without max-subtract is safe.
__global__ __launch_bounds__(256) void pool_attn_part_k(
    const float* __restrict__ qpool, const float* __restrict__ KV,
    float* __restrict__ PART) {
  __shared__ float qh[DH];
  __shared__ float ps[256];
  __shared__ float op[4][DH];
  __shared__ float red[8];
  int bh = blockIdx.x, c = blockIdx.y;
  int b = bh>>3, h = bh&7;
  int Lb = c_L[b];
  int tid = threadIdx.x;
  if (tid < DH) qh[tid] = qpool[h*DH + tid];
  __syncthreads();
  int kk = c*256 + tid;
  float p = 0.f;
  if (kk < Lb) {
    const float4* kp = (const float4*)(KV + (size_t)(c_off[b]+kk)*1024 + h*DH);
    float a = 0.f;
    #pragma unroll
    for (int dd=0; dd<16; ++dd) {
      float4 kv = kp[dd];
      a += kv.x*qh[dd*4] + kv.y*qh[dd*4+1] + kv.z*qh[dd*4+2] + kv.w*qh[dd*4+3];
    }
    p = __expf(a*0.125f);
  }
  ps[tid] = p;
  float s = p, s2 = 0.f;
  reduce2_256(s, s2, red);     // s = chunk exp-sum; syncs also publish ps
  int wvv = tid >> 6, lane = tid & 63;
  float o = 0.f;
  int kb = c*256 + wvv*64;
  const float* vb = KV + (size_t)c_off[b]*1024 + 512 + h*DH + lane;
  for (int j = 0; j < 64; ++j) {
    int key = kb + j;
    if (key < Lb) o += ps[wvv*64+j] * vb[(size_t)key*1024];
  }
  op[wvv][lane] = o;
  __syncthreads();
  if (tid < DH)
    PART[((size_t)bh*4 + c)*66 + tid] = op[0][tid]+op[1][tid]+op[2][tid]+op[3][tid];
  if (tid == 64)
    PART[((size_t)bh*4 + c)*66 + 64] = s;
}

// ---- pooling cross-attention, phase 2: combine chunks ----
__global__ __launch_bounds__(64) void pool_attn_comb_k(
    const float* __restrict__ PART, float* __restrict__ O) {
  int bh = blockIdx.x, b = bh>>3, h = bh&7, d = threadIdx.x;
  float o = 0.f, sum = 0.f;
  #pragma unroll
  for (int c = 0; c < 4; ++c) {
    o   += PART[((size_t)bh*4 + c)*66 + d];
    sum += PART[((size_t)bh*4 + c)*66 + 64];
  }
  O[(size_t)b*DIM + h*DH + d] = o / sum;
}

// ---- tiny projection Y[8,512] = X[8,512] @ W[512,512]^T, column-split ----
__global__ __launch_bounds__(256) void proj512_k(
    const float* __restrict__ X, const float* __restrict__ W, float* __restrict__ Y) {
  __shared__ float xr[DIM];
  int b = blockIdx.x, tid = threadIdx.x;
  for (int i=tid;i<DIM;i+=256) xr[i] = X[(size_t)b*DIM+i];
  __syncthreads();
  if (tid < 128) {
    int n = blockIdx.y*128 + tid;
    const float4* wr = (const float4*)(W + (size_t)n*DIM);
    float a=0.f;
    for (int k=0;k<DIM/4;++k) { float4 w4 = wr[k]; a += w4.x*xr[k*4]+w4.y*xr[k*4+1]+w4.z*xr[k*4+2]+w4.w*xr[k*4+3]; }
    Y[(size_t)b*DIM+n]=a;
  }
}

// ---- final LN + classifier head, column-split ----
__global__ __launch_bounds__(256) void head_out_k(
    const float* __restrict__ X, const float* __restrict__ g,
    const float* __restrict__ W, float* __restrict__ out) {
  __shared__ float xr[DIM];
  __shared__ float red[8];
  int b = blockIdx.x, tid = threadIdx.x;
  float s=0.f, s2=0.f;
  for (int i=tid;i<DIM;i+=256){ float v=X[(size_t)b*DIM+i]; s+=v; s2+=v*v; }
  reduce2_256(s, s2, red);
  float mu=s*(1.f/DIM), rs=rsqrtf(fmaxf(s2*(1.f/DIM)-mu*mu,0.f)+1e-5f);
  for (int i=tid;i<DIM;i+=256) xr[i]=(X[(size_t)b*DIM+i]-mu)*rs*g[i];
  __syncthreads();
  if (tid < 125) {
    int n = blockIdx.y*125 + tid;
    const float4* wr = (const float4*)(W + (size_t)n*DIM);
    float a=0.f;
    for (int k=0;k<DIM/4;++k){ float4 w4=wr[k]; a += w4.x*xr[k*4]+w4.y*xr[k*4+1]+w4.z*xr[k*4+2]+w4.w*xr[k*4+3]; }
    out[(size_t)b*NC+n]=a;
  }
}

extern "C" void kernel_launch(void* const* d_in, const int* in_sizes, int n_in,
                              void* d_out, int out_size, void* d_ws, size_t ws_size,
                              hipStream_t stream) {
  const float* images  = (const float*)d_in[0];
  const float* pe_ln1_w= (const float*)d_in[1];
  const float* pe_ln1_b= (const float*)d_in[2];
  const float* pe_w    = (const float*)d_in[3];
  const float* pe_b    = (const float*)d_in[4];
  const float* pe_ln2_w= (const float*)d_in[5];
  const float* pe_ln2_b= (const float*)d_in[6];
  const float* pos_h   = (const float*)d_in[7];
  const float* pos_w   = (const float*)d_in[8];
  const float* attn_ln = (const float*)d_in[9];
  const float* wq      = (const float*)d_in[10];
  const float* wk      = (const float*)d_in[11];
  const float* wvp     = (const float*)d_in[12];
  const float* qn      = (const float*)d_in[13];
  const float* kn      = (const float*)d_in[14];
  const float* wo      = (const float*)d_in[15];
  const float* ff_ln   = (const float*)d_in[16];
  const float* ff_w1   = (const float*)d_in[17];
  const float* ff_b1   = (const float*)d_in[18];
  const float* ff_w2   = (const float*)d_in[19];
  const float* ff_b2   = (const float*)d_in[20];
  const float* final_ln= (const float*)d_in[21];
  const float* pool_q  = (const float*)d_in[22];
  const float* pool_ln = (const float*)d_in[23];
  const float* pool_wq = (const float*)d_in[24];
  const float* pool_wk = (const float*)d_in[25];
  const float* pool_wv = (const float*)d_in[26];
  const float* pool_qn = (const float*)d_in[27];
  const float* pool_kn = (const float*)d_in[28];
  const float* pool_wo = (const float*)d_in[29];
  const float* head_ln = (const float*)d_in[30];
  const float* head_w  = (const float*)d_in[31];
  (void)ws_size; (void)in_sizes; (void)n_in; (void)out_size;

  char* p = (char*)d_ws;
  ushort* WQKVc = (ushort*)p; p += (size_t)6*1536*512*2;   // 9.44 MB
  ushort* WOc   = (ushort*)p; p += (size_t)6*512*512*2;    // 3.15 MB
  ushort* W1c   = (ushort*)p; p += (size_t)6*2048*512*2;   // 12.6 MB
  ushort* W2c   = (ushort*)p; p += (size_t)6*512*2048*2;   // 12.6 MB
  ushort* PEWc  = (ushort*)p; p += (size_t)512*768*2;      // 0.79 MB
  ushort* PKVc  = (ushort*)p; p += (size_t)1024*512*2;     // 1.05 MB
  float*  T     = (float*)p;  p += (size_t)MPACK*DIM*4;    // 11.0 MB
  ushort* XN    = (ushort*)p; p += (size_t)MPACK*DIM*2;    // 5.5 MB
  float*  KVb   = (float*)p;  p += (size_t)MPACK*1024*4;   // 22.0 MB (pool KV)
  ushort* Qh    = (ushort*)p; p += (size_t)64*LMAXS*DH*2;  // 8.4 MB
  ushort* Kh    = (ushort*)p; p += (size_t)64*LMAXS*DH*2;
  ushort* Vh    = (ushort*)p; p += (size_t)64*LMAXS*DH*2;
  ushort* VhT   = (ushort*)p; p += (size_t)64*64*LMAXS*2;  // 8.4 MB
  ushort* FFH   = (ushort*)p; p += (size_t)MPACK*MLP*2;    // 22.0 MB (aliases TOK, ATTO)
  ushort* TOK   = FFH;
  ushort* ATTO  = FFH;
  float*  QP    = (float*)p;  p += DIM*4;
  float*  QPOOL = (float*)p;  p += DIM*4;
  float*  POOLO = (float*)p;  p += NB*DIM*4;
  float*  POOLED= (float*)p;  p += NB*DIM*4;
  float*  PART  = (float*)p;  p += (size_t)64*4*66*4;

  // ---- weight conversion (same work every call) ----
  cvt_qkv_k<<<(6*1536*512+255)/256, 256, 0, stream>>>(wq, wk, wvp, WQKVc);
  cvt_k<<<(6*512*512+255)/256, 256, 0, stream>>>(wo, WOc, 6*512*512);
  cvt_k<<<(6*2048*512+255)/256, 256, 0, stream>>>(ff_w1, W1c, 6*2048*512);
  cvt_k<<<(6*512*2048+255)/256, 256, 0, stream>>>(ff_w2, W2c, 6*512*2048);
  cvt_k<<<(512*768+255)/256, 256, 0, stream>>>(pe_w, PEWc, 512*768);
  cvt_pool_k<<<(1024*512+255)/256, 256, 0, stream>>>(pool_wk, pool_wv, PKVc);

  // ---- patch embed (packed) ----
  pack_ln1_k<<<MPACK, 256, 0, stream>>>(images, pe_ln1_w, pe_ln1_b, TOK);
  gemm_bf<0,0><<<dim3(4, MPACK/128), 256, 0, stream>>>(TOK, PEWc, pe_b, T, MPACK, DIM, PDIM);
  ln2_pos_k<<<MPACK, 256, 0, stream>>>(T, pe_ln2_w, pe_ln2_b, pos_h, pos_w);

  // ---- transformer layers ----
  for (int l = 0; l < DEPTH; ++l) {
    row_ln_bf_k<<<MPACK, 256, 0, stream>>>(T, attn_ln + l*DIM, XN, DIM);
    gemm_qkv_k<0><<<dim3(12, MPACK/128), 256, 0, stream>>>(
        XN, WQKVc + (size_t)l*1536*512, qn + l*DH, kn + l*DH, Qh, Kh, Vh, nullptr, 1536);
    vtrans_k<<<dim3(64, 16), 256, 0, stream>>>(Vh, VhT);
    attn_mfma_k<<<dim3(64, 16), 256, 0, stream>>>(Qh, Kh, VhT, ATTO);
    gemm_bf<0,1><<<dim3(4, MPACK/128, 2), 256, 0, stream>>>(ATTO, WOc + (size_t)l*512*512, nullptr, T, MPACK, DIM, DIM);
    row_ln_bf_k<<<MPACK, 256, 0, stream>>>(T, ff_ln + l*DIM, XN, DIM);
    gemm_bf<1,2><<<dim3(16, MPACK/128), 256, 0, stream>>>(XN, W1c + (size_t)l*MLP*DIM, ff_b1 + l*MLP, FFH, MPACK, MLP, DIM);
    gemm_bf<0,1><<<dim3(4, MPACK/128, 4), 256, 0, stream>>>(FFH, W2c + (size_t)l*DIM*MLP, ff_b2 + l*DIM, T, MPACK, DIM, MLP);
  }

  // ---- pooling head ----
  row_ln_bf_k<<<MPACK, 256, 0, stream>>>(T, final_ln, XN, DIM);
  pool_prep_a_k<<<8, 256, 0, stream>>>(pool_q, pool_ln, pool_wq, QP);
  pool_prep_b_k<<<1, 512, 0, stream>>>(QP, pool_qn, QPOOL);
  gemm_qkv_k<1><<<dim3(8, MPACK/128), 256, 0, stream>>>(
      XN, PKVc, pool_kn, nullptr, nullptr, nullptr, nullptr, KVb, 1024);
  pool_attn_part_k<<<dim3(64, 4), 256, 0, stream>>>(QPOOL, KVb, PART);
  pool_attn_comb_k<<<64, 64, 0, stream>>>(PART, POOLO);
  proj512_k<<<dim3(8, 4), 256, 0, stream>>>(POOLO, pool_wo, POOLED);
  head_out_k<<<dim3(8, 8), 256, 0, stream>>>(POOLED, head_ln, head_w, (float*)d_out);
}

// Round 6
// 1445.378 us; speedup vs baseline: 3.9661x; 1.1208x over previous
//
#include <hip/hip_runtime.h>
#include <math.h>

#define LMAXS 1024
#define NB 8
#define DIM 512
#define HEADS 8
#define DH 64
#define DEPTH 6
#define MLP 2048
#define NC 1000
#define PDIM 768
#define MPACK 5376   // 5360 valid rows padded to 42*128
#define MVALID 5360

typedef __attribute__((ext_vector_type(8))) short short8;
typedef __attribute__((ext_vector_type(4))) float floatx4;
typedef unsigned short ushort;

// per-image patch grid width, valid token count L, packed row offset
__constant__ int c_w[8]   = {32,24,32,24,28,32,16,20};
__constant__ int c_L[8]   = {1024,768,896,576,560,512,384,640};
__constant__ int c_off[9] = {0,1024,1792,2688,3264,3824,4336,4720,5360};

__device__ __forceinline__ int row2img(int r) {
  int b = 0;
  #pragma unroll
  for (int i = 1; i < 8; ++i) if (r >= c_off[i]) b = i;
  return b;
}

__device__ __forceinline__ ushort f2bf(float x) {
  unsigned int u = __float_as_uint(x);
  u += 0x7fff + ((u >> 16) & 1);          // RNE
  return (ushort)(u >> 16);
}

// async global->LDS, 16B per lane; LDS dest must be wave-uniform base + lane*16
#define GLOAD_LDS16(gp, lp) \
  __builtin_amdgcn_global_load_lds((const __attribute__((address_space(1))) void*)(gp), \
                                   (__attribute__((address_space(3))) void*)(lp), 16, 0, 0)

// ---- block-wide (256 thr) sum + sumsq reduction ----
__device__ __forceinline__ void reduce2_256(float& s, float& s2, float* red) {
  #pragma unroll
  for (int off = 32; off; off >>= 1) {
    s  += __shfl_xor(s, off);
    s2 += __shfl_xor(s2, off);
  }
  int wv = threadIdx.x >> 6;
  if ((threadIdx.x & 63) == 0) { red[wv*2] = s; red[wv*2+1] = s2; }
  __syncthreads();
  s  = red[0] + red[2] + red[4] + red[6];
  s2 = red[1] + red[3] + red[5] + red[7];
  __syncthreads();
}

// ---- weight conversion fp32 -> bf16 ----
__global__ __launch_bounds__(256) void cvt_k(const float* __restrict__ s, ushort* __restrict__ d, int n) {
  int i = blockIdx.x*256 + threadIdx.x;
  if (i < n) d[i] = f2bf(s[i]);
}
// interleave wq/wk/wv -> [6][1536][512]
__global__ __launch_bounds__(256) void cvt_qkv_k(
    const float* __restrict__ wq, const float* __restrict__ wk, const float* __restrict__ wv,
    ushort* __restrict__ d) {
  int i = blockIdx.x*256 + threadIdx.x;
  if (i >= 6*1536*512) return;
  int l = i / (1536*512), r = (i / 512) % 1536, k = i & 511;
  const float* src = (r < 512) ? wq : (r < 1024) ? wk : wv;
  int rr = r & 511;
  d[i] = f2bf(src[(size_t)l*DIM*DIM + (size_t)rr*DIM + k]);
}
// stack pool_wk/pool_wv -> [1024][512]
__global__ __launch_bounds__(256) void cvt_pool_k(
    const float* __restrict__ wk, const float* __restrict__ wv, ushort* __restrict__ d) {
  int i = blockIdx.x*256 + threadIdx.x;
  if (i >= 1024*512) return;
  int r = i >> 9, k = i & 511;
  d[i] = f2bf(r < 512 ? wk[(size_t)r*DIM + k] : wv[(size_t)(r-512)*DIM + k]);
}

// ---- patchify + LN(768) -> bf16 packed tokens ----
__global__ __launch_bounds__(256) void pack_ln1_k(
    const float* __restrict__ images, const float* __restrict__ g,
    const float* __restrict__ bb, ushort* __restrict__ tok) {
  int r = blockIdx.x;
  ushort* out = tok + (size_t)r * PDIM;
  if (r >= MVALID) {
    for (int i = threadIdx.x; i < PDIM; i += 256) out[i] = 0;
    return;
  }
  int b = row2img(r), l = r - c_off[b];
  int wgrid = c_w[b];
  __shared__ float vals[PDIM];
  __shared__ float red[8];
  int hp = l / wgrid, wp = l % wgrid;
  const float* base = images + (size_t)b*3*512*512 + (size_t)hp*16*512 + wp*16;
  float s = 0.f, s2 = 0.f;
  for (int i = threadIdx.x; i < PDIM; i += 256) {
    int c = i >> 8, rr = (i >> 4) & 15, cc = i & 15;
    float v = base[(size_t)c*512*512 + rr*512 + cc];
    vals[i] = v; s += v; s2 += v*v;
  }
  reduce2_256(s, s2, red);
  float mu = s * (1.f/PDIM);
  float rs = rsqrtf(fmaxf(s2*(1.f/PDIM) - mu*mu, 0.f) + 1e-5f);
  for (int i = threadIdx.x; i < PDIM; i += 256)
    out[i] = f2bf((vals[i]-mu)*rs*g[i] + bb[i]);
}

// ---- bf16 MFMA GEMM: C[M,N] = act(A[M,K] @ W[N,K]^T + bias) ----
// 128x128 tile, BK=64, xor-swizzled global_load_lds staging.
// LDS layout: 16B block b holds (row=b>>3, seg=(b&7)^(row&7)); read row r seg s at r*64+(s^(r&7))*8.
// OUT: 0 = f32 store, 1 = f32 atomic-accumulate (split-K via gridDim.z), 2 = bf16 store.
template<int ACT, int OUT>
__global__ __launch_bounds__(256) void gemm_bf(
    const ushort* __restrict__ A, const ushort* __restrict__ W,
    const float* __restrict__ bias, void* __restrict__ Cv,
    int M, int N, int K) {
  __shared__ ushort As[128*64];
  __shared__ ushort Ws[128*64];
  int tid = threadIdx.x;
  int row0 = blockIdx.y*128, col0 = blockIdx.x*128;
  int lane = tid & 63, l15 = lane & 15, quad = lane >> 4;
  int wv = tid >> 6, wm = wv >> 1, wn = wv & 1;
  int sw = l15 & 7;
  int segA = (quad ^ sw) * 8, segB = segA ^ 32;
  const ushort *Ap[4], *Wp[4];
  #pragma unroll
  for (int j = 0; j < 4; ++j) {
    int blk = j*256 + tid;
    int r = blk >> 3, s = ((blk & 7) ^ (r & 7)) * 8;
    Ap[j] = A + (size_t)(row0 + r)*K + s;
    Wp[j] = W + (size_t)(col0 + r)*K + s;
  }
  int ksl = K / gridDim.z;
  int kb0 = blockIdx.z * ksl;
  floatx4 acc[4][4] = {};
  for (int k0 = kb0; k0 < kb0 + ksl; k0 += 64) {
    __syncthreads();
    #pragma unroll
    for (int j = 0; j < 4; ++j) {
      GLOAD_LDS16(Ap[j] + k0, &As[(j*256+tid)*8]);
      GLOAD_LDS16(Wp[j] + k0, &Ws[(j*256+tid)*8]);
    }
    __syncthreads();
    #pragma unroll
    for (int w = 0; w < 2; ++w) {
      int sg = w ? segB : segA;
      short8 af[4], bf[4];
      #pragma unroll
      for (int i = 0; i < 4; ++i) af[i] = *(const short8*)&As[(wm*64 + i*16 + l15)*64 + sg];
      #pragma unroll
      for (int j = 0; j < 4; ++j) bf[j] = *(const short8*)&Ws[(wn*64 + j*16 + l15)*64 + sg];
      #pragma unroll
      for (int i = 0; i < 4; ++i)
        #pragma unroll
        for (int j = 0; j < 4; ++j)
          acc[i][j] = __builtin_amdgcn_mfma_f32_16x16x32_bf16(af[i], bf[j], acc[i][j], 0, 0, 0);
    }
  }
  int rb = row0 + wm*64 + quad*4;
  int cb = col0 + wn*64 + l15;
  bool addb = (bias != nullptr) && (blockIdx.z == 0);
  #pragma unroll
  for (int j = 0; j < 4; ++j) {
    int cc = cb + j*16;
    float bsum = addb ? bias[cc] : 0.f;
    #pragma unroll
    for (int i = 0; i < 4; ++i) {
      int rr = rb + i*16;
      #pragma unroll
      for (int reg = 0; reg < 4; ++reg) {
        float v = acc[i][j][reg] + bsum;
        if (ACT == 1) v = 0.5f*v*(1.f + erff(v*0.70710678118654752f));
        size_t idx = (size_t)(rr + reg)*N + cc;
        if (OUT == 0)      ((float*)Cv)[idx] = v;
        else if (OUT == 1) unsafeAtomicAdd(&((float*)Cv)[idx], v);
        else               ((ushort*)Cv)[idx] = f2bf(v);
      }
    }
  }
}

// ---- QKV / pool-KV GEMM with fused per-head LN in epilogue (BK=64 swizzled) ----
// POOL=0: N=1536, writes Qh/Kh/Vh bf16 [b,h,l,64] (LN on Q,K units).
// POOL=1: N=1024, writes KV fp32 [row][1024] (LN on K units = cols<512).
template<int POOL>
__global__ __launch_bounds__(256) void gemm_qkv_k(
    const ushort* __restrict__ A, const ushort* __restrict__ W,
    const float* __restrict__ gq, const float* __restrict__ gk,
    ushort* __restrict__ Qh, ushort* __restrict__ Kh, ushort* __restrict__ Vh,
    float* __restrict__ KV, int N) {
  const int K = DIM;
  __shared__ ushort As[128*64];
  __shared__ ushort Ws[128*64];
  int tid = threadIdx.x;
  int row0 = blockIdx.y*128, col0 = blockIdx.x*128;
  int lane = tid & 63, l15 = lane & 15, quad = lane >> 4;
  int wv = tid >> 6, wm = wv >> 1, wn = wv & 1;
  int sw = l15 & 7;
  int segA = (quad ^ sw) * 8, segB = segA ^ 32;
  const ushort *Ap[4], *Wp[4];
  #pragma unroll
  for (int j = 0; j < 4; ++j) {
    int blk = j*256 + tid;
    int r = blk >> 3, s = ((blk & 7) ^ (r & 7)) * 8;
    Ap[j] = A + (size_t)(row0 + r)*K + s;
    Wp[j] = W + (size_t)(col0 + r)*K + s;
  }
  floatx4 acc[4][4] = {};
  for (int k0 = 0; k0 < K; k0 += 64) {
    __syncthreads();
    #pragma unroll
    for (int j = 0; j < 4; ++j) {
      GLOAD_LDS16(Ap[j] + k0, &As[(j*256+tid)*8]);
      GLOAD_LDS16(Wp[j] + k0, &Ws[(j*256+tid)*8]);
    }
    __syncthreads();
    #pragma unroll
    for (int w = 0; w < 2; ++w) {
      int sg = w ? segB : segA;
      short8 af[4], bf[4];
      #pragma unroll
      for (int i = 0; i < 4; ++i) af[i] = *(const short8*)&As[(wm*64 + i*16 + l15)*64 + sg];
      #pragma unroll
      for (int j = 0; j < 4; ++j) bf[j] = *(const short8*)&Ws[(wn*64 + j*16 + l15)*64 + sg];
      #pragma unroll
      for (int i = 0; i < 4; ++i)
        #pragma unroll
        for (int j = 0; j < 4; ++j)
          acc[i][j] = __builtin_amdgcn_mfma_f32_16x16x32_bf16(af[i], bf[j], acc[i][j], 0, 0, 0);
    }
  }
  // epilogue: wave's 64-col span = exactly one head-unit
  int unit = (col0 >> 6) + wn;              // POOL=0: 0..23 (Q/K/V x head); POOL=1: 0..15 (K/V x head)
  bool needln = POOL ? (unit < 8) : (unit < 16);
  const float* gain = POOL ? gq : (unit < 8 ? gq : gk);
  #pragma unroll
  for (int i = 0; i < 4; ++i) {
    float s[4] = {0,0,0,0}, s2[4] = {0,0,0,0};
    if (needln) {
      #pragma unroll
      for (int j = 0; j < 4; ++j)
        #pragma unroll
        for (int reg = 0; reg < 4; ++reg) {
          float v = acc[i][j][reg];
          s[reg] += v; s2[reg] += v*v;
        }
      #pragma unroll
      for (int reg = 0; reg < 4; ++reg)
        #pragma unroll
        for (int off = 1; off < 16; off <<= 1) {
          s[reg]  += __shfl_xor(s[reg],  off);
          s2[reg] += __shfl_xor(s2[reg], off);
        }
    }
    #pragma unroll
    for (int reg = 0; reg < 4; ++reg) {
      int r = row0 + wm*64 + i*16 + quad*4 + reg;
      if (r >= MVALID) continue;
      float mu = s[reg]*(1.f/64.f);
      float rs = rsqrtf(fmaxf(s2[reg]*(1.f/64.f) - mu*mu, 0.f) + 1e-5f);
      int b = row2img(r), l = r - c_off[b];
      #pragma unroll
      for (int j = 0; j < 4; ++j) {
        int dh = j*16 + l15;
        float v = acc[i][j][reg];
        if (needln) v = (v - mu)*rs*gain[dh];
        if (POOL) {
          KV[(size_t)r*1024 + unit*64 + dh] = v;
        } else {
          int h = unit & 7;
          size_t dst = ((size_t)(b*8+h)*LMAXS + l)*64 + dh;
          if (unit < 8)       Qh[dst] = f2bf(v);
          else if (unit < 16) Kh[dst] = f2bf(v);
          else                Vh[dst] = f2bf(v);
        }
      }
    }
  }
}

// ---- row LayerNorm (width n), fp32 X -> bf16 Y ----
__global__ __launch_bounds__(256) void row_ln_bf_k(
    const float* __restrict__ X, const float* __restrict__ g,
    ushort* __restrict__ Y, int n) {
  __shared__ float red[8];
  size_t base = (size_t)blockIdx.x * n;
  float s=0.f, s2=0.f;
  for (int i = threadIdx.x; i < n; i += 256) { float v = X[base+i]; s += v; s2 += v*v; }
  reduce2_256(s, s2, red);
  float mu = s/n, rs = rsqrtf(fmaxf(s2/n - mu*mu, 0.f) + 1e-5f);
  for (int i = threadIdx.x; i < n; i += 256)
    Y[base+i] = f2bf((X[base+i]-mu)*rs*g[i]);
}

// ---- LN2 + bias + pos embed, packed, in place on fp32 T ----
__global__ __launch_bounds__(256) void ln2_pos_k(
    float* __restrict__ T, const float* __restrict__ g, const float* __restrict__ bb,
    const float* __restrict__ ph, const float* __restrict__ pw) {
  int r = blockIdx.x;
  float* x = T + (size_t)r * DIM;
  if (r >= MVALID) {
    for (int i = threadIdx.x; i < DIM; i += 256) x[i] = 0.f;
    return;
  }
  int b = row2img(r), l = r - c_off[b];
  __shared__ float red[8];
  int wgrid = c_w[b];
  int hi = l / wgrid, wi = l % wgrid;
  float s=0.f, s2=0.f;
  for (int i = threadIdx.x; i < DIM; i += 256) { float v = x[i]; s+=v; s2+=v*v; }
  reduce2_256(s, s2, red);
  float mu = s*(1.f/DIM), rs = rsqrtf(fmaxf(s2*(1.f/DIM)-mu*mu, 0.f)+1e-5f);
  for (int i = threadIdx.x; i < DIM; i += 256)
    x[i] = (x[i]-mu)*rs*g[i] + bb[i] + ph[hi*DIM+i] + pw[wi*DIM+i];
}

// ---- V transpose per head: Vh [bh][l][64] -> VhT [bh][64][LMAX] ----
__global__ __launch_bounds__(256) void vtrans_k(
    const ushort* __restrict__ Vh, ushort* __restrict__ VhT) {
  int bh = blockIdx.x, b = bh >> 3;
  int lt = blockIdx.y;
  if (lt*64 >= c_L[b]) return;
  __shared__ ushort t[64][72];
  int tid = threadIdx.x;
  int row = tid >> 2, seg = (tid & 3)*16;
  const ushort* src = Vh + ((size_t)bh*LMAXS + lt*64 + row)*64 + seg;
  *(short8*)&t[row][seg]   = *(const short8*)src;
  *(short8*)&t[row][seg+8] = *(const short8*)(src+8);
  __syncthreads();
  int dh = tid >> 2, ks = (tid & 3)*16;
  short8 o0, o1;
  #pragma unroll
  for (int jj = 0; jj < 8; ++jj) o0[jj] = (short)t[ks+jj][dh];
  #pragma unroll
  for (int jj = 0; jj < 8; ++jj) o1[jj] = (short)t[ks+8+jj][dh];
  ushort* dst = VhT + ((size_t)bh*64 + dh)*LMAXS + lt*64 + ks;
  *(short8*)dst     = o0;
  *(short8*)(dst+8) = o1;
}

// ---- bf16 MFMA flash attention v2 ----
// Max-free softmax (|s/8|<=8 after unit-gain head-LN), xor-swizzled global_load_lds staging,
// per-lane l-sum partials reduced once after the K-loop.
__global__ __launch_bounds__(256) void attn_mfma_k(
    const ushort* __restrict__ Qh, const ushort* __restrict__ Kh,
    const ushort* __restrict__ VhT, ushort* __restrict__ O) {
  int bh = blockIdx.x, b = bh >> 3, h = bh & 7;
  int Lb = c_L[b];
  int qt = blockIdx.y;
  if (qt * 64 >= Lb) return;
  __shared__ ushort Ks[64*64];            // swizzled: row r, seg s at r*64 + (s^(r&7))*8
  __shared__ ushort Vt[64*64];            // rows = dh, cols = keys (same swizzle)
  __shared__ ushort Pb[4][16][68];        // per-wave P, stride 68 (quads hit distinct bank octets)
  int tid = threadIdx.x, wv = tid >> 6, lane = tid & 63;
  int quad = lane >> 4, l15 = lane & 15;
  int sw = l15 & 7;
  int segA = (quad ^ sw) * 8, segB = segA ^ 32;
  int q0 = qt*64 + wv*16;
  bool active = q0 < Lb;                  // L % 16 == 0: active waves fully valid
  const ushort* qhb = Qh + (size_t)bh * LMAXS * DH;
  const ushort* khb = Kh + (size_t)bh * LMAXS * DH;
  const ushort* vtb = VhT + (size_t)bh * DH * LMAXS;
  short8 aq0 = {}, aq1 = {};
  if (active) {
    const ushort* qp = qhb + (size_t)(q0 + l15) * DH;
    aq0 = *(const short8*)(qp + quad*8);
    aq1 = *(const short8*)(qp + 32 + quad*8);
  }
  // staging: 512 16B-blocks per matrix, 2 per thread
  int blk0 = tid, blk1 = tid + 256;
  int kr0 = blk0 >> 3, s0 = ((blk0 & 7) ^ (kr0 & 7)) * 8;
  int kr1 = blk1 >> 3, s1 = ((blk1 & 7) ^ (kr1 & 7)) * 8;
  const ushort* kg0 = khb + kr0*DH + s0;
  const ushort* kg1 = khb + kr1*DH + s1;
  const ushort* vg0 = vtb + (size_t)kr0*LMAXS + s0;
  const ushort* vg1 = vtb + (size_t)kr1*LMAXS + s1;
  float lsum[4] = {0.f,0.f,0.f,0.f};
  floatx4 o[4] = {};
  for (int kc = 0; kc < Lb; kc += 64) {
    __syncthreads();
    GLOAD_LDS16(kg0 + kc*DH, &Ks[blk0*8]);
    GLOAD_LDS16(kg1 + kc*DH, &Ks[blk1*8]);
    GLOAD_LDS16(vg0 + kc,    &Vt[blk0*8]);
    GLOAD_LDS16(vg1 + kc,    &Vt[blk1*8]);
    __syncthreads();
    if (!active) continue;
    bool tail = (kc + 64 > Lb);
    #pragma unroll
    for (int kb = 0; kb < 4; ++kb) {
      int krow = (kb*16 + l15) * 64;
      floatx4 s = {};
      s = __builtin_amdgcn_mfma_f32_16x16x32_bf16(aq0, *(const short8*)&Ks[krow + segA], s, 0,0,0);
      s = __builtin_amdgcn_mfma_f32_16x16x32_bf16(aq1, *(const short8*)&Ks[krow + segB], s, 0,0,0);
      #pragma unroll
      for (int reg = 0; reg < 4; ++reg) {
        float x = s[reg] * 0.125f;
        if (tail && (kc + kb*16 + l15 >= Lb)) x = -1e9f;  // assignment kills any garbage-row inf
        float p = __expf(x);                               // |x|<=8 for valid keys: no max needed
        lsum[reg] += p;
        Pb[wv][quad*4+reg][kb*16+l15] = f2bf(p);
      }
    }
    short8 a0 = *(const short8*)&Pb[wv][l15][quad*8];
    short8 a1 = *(const short8*)&Pb[wv][l15][32+quad*8];
    #pragma unroll
    for (int nb = 0; nb < 4; ++nb) {
      int vrow = (nb*16 + l15) * 64;
      o[nb] = __builtin_amdgcn_mfma_f32_16x16x32_bf16(a0, *(const short8*)&Vt[vrow + segA], o[nb], 0,0,0);
      o[nb] = __builtin_amdgcn_mfma_f32_16x16x32_bf16(a1, *(const short8*)&Vt[vrow + segB], o[nb], 0,0,0);
    }
  }
  if (active) {
    float inv[4];
    #pragma unroll
    for (int reg = 0; reg < 4; ++reg) {
      float s = lsum[reg];
      s += __shfl_xor(s,1); s += __shfl_xor(s,2); s += __shfl_xor(s,4); s += __shfl_xor(s,8);
      inv[reg] = 1.f / s;
    }
    int rbase = c_off[b] + q0 + quad*4;
    #pragma unroll
    for (int nb = 0; nb < 4; ++nb)
      #pragma unroll
      for (int reg = 0; reg < 4; ++reg)
        O[(size_t)(rbase+reg)*DIM + h*DH + nb*16 + l15] = f2bf(o[nb][reg] * inv[reg]);
  }
}

// ---- pool query prep A: qp = LN(pool_q) @ pool_wq^T, column-parallel ----
__global__ __launch_bounds__(256) void pool_prep_a_k(
    const float* __restrict__ pq, const float* __restrict__ pln,
    const float* __restrict__ pwq, float* __restrict__ qp) {
  __shared__ float qln[DIM];
  __shared__ float red[8];
  int tid = threadIdx.x;
  float s=0.f, s2=0.f;
  for (int i=tid;i<DIM;i+=256){ float v=pq[i]; s+=v; s2+=v*v; }
  reduce2_256(s, s2, red);
  float mu=s*(1.f/DIM), rs=rsqrtf(fmaxf(s2*(1.f/DIM)-mu*mu,0.f)+1e-5f);
  for (int i=tid;i<DIM;i+=256) qln[i]=(pq[i]-mu)*rs*pln[i];
  __syncthreads();
  int n = blockIdx.x*64 + (tid>>2);
  int kq = (tid&3)*128;
  const float4* wr = (const float4*)(pwq + (size_t)n*DIM + kq);
  float a=0.f;
  #pragma unroll
  for (int k=0;k<32;++k) {
    float4 w4 = wr[k];
    float4 q4 = *(const float4*)&qln[kq + k*4];
    a += w4.x*q4.x + w4.y*q4.y + w4.z*q4.z + w4.w*q4.w;
  }
  a += __shfl_xor(a,1); a += __shfl_xor(a,2);
  if ((tid&3)==0) qp[n]=a;
}

// ---- pool query prep B: per-head LN on qp -> qpool ----
__global__ __launch_bounds__(512) void pool_prep_b_k(
    const float* __restrict__ qp, const float* __restrict__ pqn, float* __restrict__ qpool) {
  int h = threadIdx.x >> 6, lane = threadIdx.x & 63;
  float v = qp[h*64 + lane];
  float s = v, s2 = v*v;
  #pragma unroll
  for (int off=32; off; off>>=1) { s += __shfl_xor(s,off); s2 += __shfl_xor(s2,off); }
  float mu = s*(1.f/64), rs = rsqrtf(fmaxf(s2*(1.f/64)-mu*mu, 0.f)+1e-5f);
  qpool[h*64+lane] = (v-mu)*rs*pqn[lane];
}

// ---- pooling cross-attention, phase 1: per (bh, key-chunk) partials ----
__global__ __launch_bounds__(256) void pool_attn_part_k(
    const float* __restrict__ qpool, const float* __restrict__ KV,
    float* __restrict__ PART) {
  __shared__ float qh[DH];
  __shared__ float ps[256];
  __shared__ float op[4][DH];
  __shared__ float red[8];
  int bh = blockIdx.x, c = blockIdx.y;
  int b = bh>>3, h = bh&7;
  int Lb = c_L[b];
  int tid = threadIdx.x;
  if (tid < DH) qh[tid] = qpool[h*DH + tid];
  __syncthreads();
  int kk = c*256 + tid;
  float p = 0.f;
  if (kk < Lb) {
    const float4* kp = (const float4*)(KV + (size_t)(c_off[b]+kk)*1024 + h*DH);
    float a = 0.f;
    #pragma unroll
    for (int dd=0; dd<16; ++dd) {
      float4 kv = kp[dd];
      a += kv.x*qh[dd*4] + kv.y*qh[dd*4+1] + kv.z*qh[dd*4+2] + kv.w*qh[dd*4+3];
    }
    p = __expf(a*0.125f);
  }
  ps[tid] = p;
  float s = p, s2 = 0.f;
  reduce2_256(s, s2, red);
  int wvv = tid >> 6, lane = tid & 63;
  float o = 0.f;
  int kb = c*256 + wvv*64;
  const float* vb = KV + (size_t)c_off[b]*1024 + 512 + h*DH + lane;
  for (int j = 0; j < 64; ++j) {
    int key = kb + j;
    if (key < Lb) o += ps[wvv*64+j] * vb[(size_t)key*1024];
  }
  op[wvv][lane] = o;
  __syncthreads();
  if (tid < DH)
    PART[((size_t)bh*4 + c)*66 + tid] = op[0][tid]+op[1][tid]+op[2][tid]+op[3][tid];
  if (tid == 64)
    PART[((size_t)bh*4 + c)*66 + 64] = s;
}

// ---- pooling cross-attention, phase 2: combine chunks ----
__global__ __launch_bounds__(64) void pool_attn_comb_k(
    const float* __restrict__ PART, float* __restrict__ O) {
  int bh = blockIdx.x, b = bh>>3, h = bh&7, d = threadIdx.x;
  float o = 0.f, sum = 0.f;
  #pragma unroll
  for (int c = 0; c < 4; ++c) {
    o   += PART[((size_t)bh*4 + c)*66 + d];
    sum += PART[((size_t)bh*4 + c)*66 + 64];
  }
  O[(size_t)b*DIM + h*DH + d] = o / sum;
}

// ---- tiny projection Y[8,512] = X[8,512] @ W[512,512]^T, column-split ----
__global__ __launch_bounds__(256) void proj512_k(
    const float* __restrict__ X, const float* __restrict__ W, float* __restrict__ Y) {
  __shared__ float xr[DIM];
  int b = blockIdx.x, tid = threadIdx.x;
  for (int i=tid;i<DIM;i+=256) xr[i] = X[(size_t)b*DIM+i];
  __syncthreads();
  if (tid < 128) {
    int n = blockIdx.y*128 + tid;
    const float4* wr = (const float4*)(W + (size_t)n*DIM);
    float a=0.f;
    for (int k=0;k<DIM/4;++k) { float4 w4 = wr[k]; a += w4.x*xr[k*4]+w4.y*xr[k*4+1]+w4.z*xr[k*4+2]+w4.w*xr[k*4+3]; }
    Y[(size_t)b*DIM+n]=a;
  }
}

// ---- final LN + classifier head, column-split ----
__global__ __launch_bounds__(256) void head_out_k(
    const float* __restrict__ X, const float* __restrict__ g,
    const float* __restrict__ W, float* __restrict__ out) {
  __shared__ float xr[DIM];
  __shared__ float red[8];
  int b = blockIdx.x, tid = threadIdx.x;
  float s=0.f, s2=0.f;
  for (int i=tid;i<DIM;i+=256){ float v=X[(size_t)b*DIM+i]; s+=v; s2+=v*v; }
  reduce2_256(s, s2, red);
  float mu=s*(1.f/DIM), rs=rsqrtf(fmaxf(s2*(1.f/DIM)-mu*mu,0.f)+1e-5f);
  for (int i=tid;i<DIM;i+=256) xr[i]=(X[(size_t)b*DIM+i]-mu)*rs*g[i];
  __syncthreads();
  if (tid < 125) {
    int n = blockIdx.y*125 + tid;
    const float4* wr = (const float4*)(W + (size_t)n*DIM);
    float a=0.f;
    for (int k=0;k<DIM/4;++k){ float4 w4=wr[k]; a += w4.x*xr[k*4]+w4.y*xr[k*4+1]+w4.z*xr[k*4+2]+w4.w*xr[k*4+3]; }
    out[(size_t)b*NC+n]=a;
  }
}

extern "C" void kernel_launch(void* const* d_in, const int* in_sizes, int n_in,
                              void* d_out, int out_size, void* d_ws, size_t ws_size,
                              hipStream_t stream) {
  const float* images  = (const float*)d_in[0];
  const float* pe_ln1_w= (const float*)d_in[1];
  const float* pe_ln1_b= (const float*)d_in[2];
  const float* pe_w    = (const float*)d_in[3];
  const float* pe_b    = (const float*)d_in[4];
  const float* pe_ln2_w= (const float*)d_in[5];
  const float* pe_ln2_b= (const float*)d_in[6];
  const float* pos_h   = (const float*)d_in[7];
  const float* pos_w   = (const float*)d_in[8];
  const float* attn_ln = (const float*)d_in[9];
  const float* wq      = (const float*)d_in[10];
  const float* wk      = (const float*)d_in[11];
  const float* wvp     = (const float*)d_in[12];
  const float* qn      = (const float*)d_in[13];
  const float* kn      = (const float*)d_in[14];
  const float* wo      = (const float*)d_in[15];
  const float* ff_ln   = (const float*)d_in[16];
  const float* ff_w1   = (const float*)d_in[17];
  const float* ff_b1   = (const float*)d_in[18];
  const float* ff_w2   = (const float*)d_in[19];
  const float* ff_b2   = (const float*)d_in[20];
  const float* final_ln= (const float*)d_in[21];
  const float* pool_q  = (const float*)d_in[22];
  const float* pool_ln = (const float*)d_in[23];
  const float* pool_wq = (const float*)d_in[24];
  const float* pool_wk = (const float*)d_in[25];
  const float* pool_wv = (const float*)d_in[26];
  const float* pool_qn = (const float*)d_in[27];
  const float* pool_kn = (const float*)d_in[28];
  const float* pool_wo = (const float*)d_in[29];
  const float* head_ln = (const float*)d_in[30];
  const float* head_w  = (const float*)d_in[31];
  (void)ws_size; (void)in_sizes; (void)n_in; (void)out_size;

  char* p = (char*)d_ws;
  ushort* WQKVc = (ushort*)p; p += (size_t)6*1536*512*2;   // 9.44 MB
  ushort* WOc   = (ushort*)p; p += (size_t)6*512*512*2;    // 3.15 MB
  ushort* W1c   = (ushort*)p; p += (size_t)6*2048*512*2;   // 12.6 MB
  ushort* W2c   = (ushort*)p; p += (size_t)6*512*2048*2;   // 12.6 MB
  ushort* PEWc  = (ushort*)p; p += (size_t)512*768*2;      // 0.79 MB
  ushort* PKVc  = (ushort*)p; p += (size_t)1024*512*2;     // 1.05 MB
  float*  T     = (float*)p;  p += (size_t)MPACK*DIM*4;    // 11.0 MB
  ushort* XN    = (ushort*)p; p += (size_t)MPACK*DIM*2;    // 5.5 MB
  float*  KVb   = (float*)p;  p += (size_t)MPACK*1024*4;   // 22.0 MB (pool KV)
  ushort* Qh    = (ushort*)p; p += (size_t)64*LMAXS*DH*2;  // 8.4 MB
  ushort* Kh    = (ushort*)p; p += (size_t)64*LMAXS*DH*2;
  ushort* Vh    = (ushort*)p; p += (size_t)64*LMAXS*DH*2;
  ushort* VhT   = (ushort*)p; p += (size_t)64*64*LMAXS*2;  // 8.4 MB
  ushort* FFH   = (ushort*)p; p += (size_t)MPACK*MLP*2;    // 22.0 MB (aliases TOK, ATTO)
  ushort* TOK   = FFH;
  ushort* ATTO  = FFH;
  float*  QP    = (float*)p;  p += DIM*4;
  float*  QPOOL = (float*)p;  p += DIM*4;
  float*  POOLO = (float*)p;  p += NB*DIM*4;
  float*  POOLED= (float*)p;  p += NB*DIM*4;
  float*  PART  = (float*)p;  p += (size_t)64*4*66*4;

  // ---- weight conversion (same work every call) ----
  cvt_qkv_k<<<(6*1536*512+255)/256, 256, 0, stream>>>(wq, wk, wvp, WQKVc);
  cvt_k<<<(6*512*512+255)/256, 256, 0, stream>>>(wo, WOc, 6*512*512);
  cvt_k<<<(6*2048*512+255)/256, 256, 0, stream>>>(ff_w1, W1c, 6*2048*512);
  cvt_k<<<(6*512*2048+255)/256, 256, 0, stream>>>(ff_w2, W2c, 6*512*2048);
  cvt_k<<<(512*768+255)/256, 256, 0, stream>>>(pe_w, PEWc, 512*768);
  cvt_pool_k<<<(1024*512+255)/256, 256, 0, stream>>>(pool_wk, pool_wv, PKVc);

  // ---- patch embed (packed) ----
  pack_ln1_k<<<MPACK, 256, 0, stream>>>(images, pe_ln1_w, pe_ln1_b, TOK);
  gemm_bf<0,0><<<dim3(4, MPACK/128), 256, 0, stream>>>(TOK, PEWc, pe_b, T, MPACK, DIM, PDIM);
  ln2_pos_k<<<MPACK, 256, 0, stream>>>(T, pe_ln2_w, pe_ln2_b, pos_h, pos_w);

  // ---- transformer layers ----
  for (int l = 0; l < DEPTH; ++l) {
    row_ln_bf_k<<<MPACK, 256, 0, stream>>>(T, attn_ln + l*DIM, XN, DIM);
    gemm_qkv_k<0><<<dim3(12, MPACK/128), 256, 0, stream>>>(
        XN, WQKVc + (size_t)l*1536*512, qn + l*DH, kn + l*DH, Qh, Kh, Vh, nullptr, 1536);
    vtrans_k<<<dim3(64, 16), 256, 0, stream>>>(Vh, VhT);
    attn_mfma_k<<<dim3(64, 16), 256, 0, stream>>>(Qh, Kh, VhT, ATTO);
    gemm_bf<0,1><<<dim3(4, MPACK/128, 2), 256, 0, stream>>>(ATTO, WOc + (size_t)l*512*512, nullptr, T, MPACK, DIM, DIM);
    row_ln_bf_k<<<MPACK, 256, 0, stream>>>(T, ff_ln + l*DIM, XN, DIM);
    gemm_bf<1,2><<<dim3(16, MPACK/128), 256, 0, stream>>>(XN, W1c + (size_t)l*MLP*DIM, ff_b1 + l*MLP, FFH, MPACK, MLP, DIM);
    gemm_bf<0,1><<<dim3(4, MPACK/128, 4), 256, 0, stream>>>(FFH, W2c + (size_t)l*DIM*MLP, ff_b2 + l*DIM, T, MPACK, DIM, MLP);
  }

  // ---- pooling head ----
  row_ln_bf_k<<<MPACK, 256, 0, stream>>>(T, final_ln, XN, DIM);
  pool_prep_a_k<<<8, 256, 0, stream>>>(pool_q, pool_ln, pool_wq, QP);
  pool_prep_b_k<<<1, 512, 0, stream>>>(QP, pool_qn, QPOOL);
  gemm_qkv_k<1><<<dim3(8, MPACK/128), 256, 0, stream>>>(
      XN, PKVc, pool_kn, nullptr, nullptr, nullptr, nullptr, KVb, 1024);
  pool_attn_part_k<<<dim3(64, 4), 256, 0, stream>>>(QPOOL, KVb, PART);
  pool_attn_comb_k<<<64, 64, 0, stream>>>(PART, POOLO);
  proj512_k<<<dim3(8, 4), 256, 0, stream>>>(POOLO, pool_wo, POOLED);
  head_out_k<<<dim3(8, 8), 256, 0, stream>>>(POOLED, head_ln, head_w, (float*)d_out);
}

// Round 7
// 1264.702 us; speedup vs baseline: 4.5327x; 1.1429x over previous
//
#include <hip/hip_runtime.h>
#include <math.h>

#define LMAXS 1024
#define NB 8
#define DIM 512
#define HEADS 8
#define DH 64
#define DEPTH 6
#define MLP 2048
#define NC 1000
#define PDIM 768
#define MPACK 5376   // 5360 valid rows padded to 42*128
#define MVALID 5360

typedef __attribute__((ext_vector_type(8))) short short8;
typedef __attribute__((ext_vector_type(4))) float floatx4;
typedef unsigned short ushort;

// per-image patch grid width, valid token count L, packed row offset
__constant__ int c_w[8]   = {32,24,32,24,28,32,16,20};
__constant__ int c_L[8]   = {1024,768,896,576,560,512,384,640};
__constant__ int c_off[9] = {0,1024,1792,2688,3264,3824,4336,4720,5360};

__device__ __forceinline__ int row2img(int r) {
  int b = 0;
  #pragma unroll
  for (int i = 1; i < 8; ++i) if (r >= c_off[i]) b = i;
  return b;
}

__device__ __forceinline__ ushort f2bf(float x) {
  unsigned int u = __float_as_uint(x);
  u += 0x7fff + ((u >> 16) & 1);          // RNE
  return (ushort)(u >> 16);
}

// async global->LDS, 16B per lane; LDS dest must be wave-uniform base + lane*16
#define GLOAD_LDS16(gp, lp) \
  __builtin_amdgcn_global_load_lds((const __attribute__((address_space(1))) void*)(gp), \
                                   (__attribute__((address_space(3))) void*)(lp), 16, 0, 0)

// ---- block-wide (256 thr) sum + sumsq reduction ----
__device__ __forceinline__ void reduce2_256(float& s, float& s2, float* red) {
  #pragma unroll
  for (int off = 32; off; off >>= 1) {
    s  += __shfl_xor(s, off);
    s2 += __shfl_xor(s2, off);
  }
  int wv = threadIdx.x >> 6;
  if ((threadIdx.x & 63) == 0) { red[wv*2] = s; red[wv*2+1] = s2; }
  __syncthreads();
  s  = red[0] + red[2] + red[4] + red[6];
  s2 = red[1] + red[3] + red[5] + red[7];
  __syncthreads();
}

// ---- weight conversion fp32 -> bf16 ----
__global__ __launch_bounds__(256) void cvt_k(const float* __restrict__ s, ushort* __restrict__ d, int n) {
  int i = blockIdx.x*256 + threadIdx.x;
  if (i < n) d[i] = f2bf(s[i]);
}
// interleave wq/wk/wv -> [6][1536][512]
__global__ __launch_bounds__(256) void cvt_qkv_k(
    const float* __restrict__ wq, const float* __restrict__ wk, const float* __restrict__ wv,
    ushort* __restrict__ d) {
  int i = blockIdx.x*256 + threadIdx.x;
  if (i >= 6*1536*512) return;
  int l = i / (1536*512), r = (i / 512) % 1536, k = i & 511;
  const float* src = (r < 512) ? wq : (r < 1024) ? wk : wv;
  int rr = r & 511;
  d[i] = f2bf(src[(size_t)l*DIM*DIM + (size_t)rr*DIM + k]);
}
// stack pool_wk/pool_wv -> [1024][512]
__global__ __launch_bounds__(256) void cvt_pool_k(
    const float* __restrict__ wk, const float* __restrict__ wv, ushort* __restrict__ d) {
  int i = blockIdx.x*256 + threadIdx.x;
  if (i >= 1024*512) return;
  int r = i >> 9, k = i & 511;
  d[i] = f2bf(r < 512 ? wk[(size_t)r*DIM + k] : wv[(size_t)(r-512)*DIM + k]);
}

// ---- patchify + LN(768) -> bf16 packed tokens ----
__global__ __launch_bounds__(256) void pack_ln1_k(
    const float* __restrict__ images, const float* __restrict__ g,
    const float* __restrict__ bb, ushort* __restrict__ tok) {
  int r = blockIdx.x;
  ushort* out = tok + (size_t)r * PDIM;
  if (r >= MVALID) {
    for (int i = threadIdx.x; i < PDIM; i += 256) out[i] = 0;
    return;
  }
  int b = row2img(r), l = r - c_off[b];
  int wgrid = c_w[b];
  __shared__ float vals[PDIM];
  __shared__ float red[8];
  int hp = l / wgrid, wp = l % wgrid;
  const float* base = images + (size_t)b*3*512*512 + (size_t)hp*16*512 + wp*16;
  float s = 0.f, s2 = 0.f;
  for (int i = threadIdx.x; i < PDIM; i += 256) {
    int c = i >> 8, rr = (i >> 4) & 15, cc = i & 15;
    float v = base[(size_t)c*512*512 + rr*512 + cc];
    vals[i] = v; s += v; s2 += v*v;
  }
  reduce2_256(s, s2, red);
  float mu = s * (1.f/PDIM);
  float rs = rsqrtf(fmaxf(s2*(1.f/PDIM) - mu*mu, 0.f) + 1e-5f);
  for (int i = threadIdx.x; i < PDIM; i += 256)
    out[i] = f2bf((vals[i]-mu)*rs*g[i] + bb[i]);
}

// ---- bf16 MFMA GEMM: C[M,N] = act(A[M,K] @ W[N,K]^T + bias) ----
// 128x128 tile, BK=64, xor-swizzled global_load_lds staging.
// OUT: 0 = f32 store, 1 = f32 plain += (z must be 1), 2 = bf16 store,
//      3 = f32 partial store to Cv + blockIdx.z*M*N (split-K, no atomics).
template<int ACT, int OUT>
__global__ __launch_bounds__(256) void gemm_bf(
    const ushort* __restrict__ A, const ushort* __restrict__ W,
    const float* __restrict__ bias, void* __restrict__ Cv,
    int M, int N, int K) {
  __shared__ ushort As[128*64];
  __shared__ ushort Ws[128*64];
  int tid = threadIdx.x;
  int row0 = blockIdx.y*128, col0 = blockIdx.x*128;
  int lane = tid & 63, l15 = lane & 15, quad = lane >> 4;
  int wv = tid >> 6, wm = wv >> 1, wn = wv & 1;
  int sw = l15 & 7;
  int segA = (quad ^ sw) * 8, segB = segA ^ 32;
  const ushort *Ap[4], *Wp[4];
  #pragma unroll
  for (int j = 0; j < 4; ++j) {
    int blk = j*256 + tid;
    int r = blk >> 3, s = ((blk & 7) ^ (r & 7)) * 8;
    Ap[j] = A + (size_t)(row0 + r)*K + s;
    Wp[j] = W + (size_t)(col0 + r)*K + s;
  }
  int ksl = K / gridDim.z;
  int kb0 = blockIdx.z * ksl;
  floatx4 acc[4][4] = {};
  for (int k0 = kb0; k0 < kb0 + ksl; k0 += 64) {
    __syncthreads();
    #pragma unroll
    for (int j = 0; j < 4; ++j) {
      GLOAD_LDS16(Ap[j] + k0, &As[(j*256+tid)*8]);
      GLOAD_LDS16(Wp[j] + k0, &Ws[(j*256+tid)*8]);
    }
    __syncthreads();
    #pragma unroll
    for (int w = 0; w < 2; ++w) {
      int sg = w ? segB : segA;
      short8 af[4], bf[4];
      #pragma unroll
      for (int i = 0; i < 4; ++i) af[i] = *(const short8*)&As[(wm*64 + i*16 + l15)*64 + sg];
      #pragma unroll
      for (int j = 0; j < 4; ++j) bf[j] = *(const short8*)&Ws[(wn*64 + j*16 + l15)*64 + sg];
      #pragma unroll
      for (int i = 0; i < 4; ++i)
        #pragma unroll
        for (int j = 0; j < 4; ++j)
          acc[i][j] = __builtin_amdgcn_mfma_f32_16x16x32_bf16(af[i], bf[j], acc[i][j], 0, 0, 0);
    }
  }
  int rb = row0 + wm*64 + quad*4;
  int cb = col0 + wn*64 + l15;
  bool addb = (bias != nullptr) && (blockIdx.z == 0);
  float* outz = (float*)Cv + (OUT == 3 ? (size_t)blockIdx.z * M * N : 0);
  #pragma unroll
  for (int j = 0; j < 4; ++j) {
    int cc = cb + j*16;
    float bsum = addb ? bias[cc] : 0.f;
    #pragma unroll
    for (int i = 0; i < 4; ++i) {
      int rr = rb + i*16;
      #pragma unroll
      for (int reg = 0; reg < 4; ++reg) {
        float v = acc[i][j][reg] + bsum;
        if (ACT == 1) v = 0.5f*v*(1.f + erff(v*0.70710678118654752f));
        size_t idx = (size_t)(rr + reg)*N + cc;
        if (OUT == 0)      ((float*)Cv)[idx] = v;
        else if (OUT == 1) ((float*)Cv)[idx] += v;
        else if (OUT == 3) outz[idx] = v;
        else               ((ushort*)Cv)[idx] = f2bf(v);
      }
    }
  }
}

// ---- QKV / pool-KV GEMM with fused per-head LN in epilogue (BK=64 swizzled) ----
// POOL=0: N=1536, writes Qh/Kh/Vh bf16 [b,h,l,64] (LN on Q,K units).
// POOL=1: N=1024, writes KV fp32 [row][1024] (LN on K units = cols<512).
template<int POOL>
__global__ __launch_bounds__(256) void gemm_qkv_k(
    const ushort* __restrict__ A, const ushort* __restrict__ W,
    const float* __restrict__ gq, const float* __restrict__ gk,
    ushort* __restrict__ Qh, ushort* __restrict__ Kh, ushort* __restrict__ Vh,
    float* __restrict__ KV, int N) {
  const int K = DIM;
  __shared__ ushort As[128*64];
  __shared__ ushort Ws[128*64];
  int tid = threadIdx.x;
  int row0 = blockIdx.y*128, col0 = blockIdx.x*128;
  int lane = tid & 63, l15 = lane & 15, quad = lane >> 4;
  int wv = tid >> 6, wm = wv >> 1, wn = wv & 1;
  int sw = l15 & 7;
  int segA = (quad ^ sw) * 8, segB = segA ^ 32;
  const ushort *Ap[4], *Wp[4];
  #pragma unroll
  for (int j = 0; j < 4; ++j) {
    int blk = j*256 + tid;
    int r = blk >> 3, s = ((blk & 7) ^ (r & 7)) * 8;
    Ap[j] = A + (size_t)(row0 + r)*K + s;
    Wp[j] = W + (size_t)(col0 + r)*K + s;
  }
  floatx4 acc[4][4] = {};
  for (int k0 = 0; k0 < K; k0 += 64) {
    __syncthreads();
    #pragma unroll
    for (int j = 0; j < 4; ++j) {
      GLOAD_LDS16(Ap[j] + k0, &As[(j*256+tid)*8]);
      GLOAD_LDS16(Wp[j] + k0, &Ws[(j*256+tid)*8]);
    }
    __syncthreads();
    #pragma unroll
    for (int w = 0; w < 2; ++w) {
      int sg = w ? segB : segA;
      short8 af[4], bf[4];
      #pragma unroll
      for (int i = 0; i < 4; ++i) af[i] = *(const short8*)&As[(wm*64 + i*16 + l15)*64 + sg];
      #pragma unroll
      for (int j = 0; j < 4; ++j) bf[j] = *(const short8*)&Ws[(wn*64 + j*16 + l15)*64 + sg];
      #pragma unroll
      for (int i = 0; i < 4; ++i)
        #pragma unroll
        for (int j = 0; j < 4; ++j)
          acc[i][j] = __builtin_amdgcn_mfma_f32_16x16x32_bf16(af[i], bf[j], acc[i][j], 0, 0, 0);
    }
  }
  // epilogue: wave's 64-col span = exactly one head-unit
  int unit = (col0 >> 6) + wn;              // POOL=0: 0..23 (Q/K/V x head); POOL=1: 0..15 (K/V x head)
  bool needln = POOL ? (unit < 8) : (unit < 16);
  const float* gain = POOL ? gq : (unit < 8 ? gq : gk);
  #pragma unroll
  for (int i = 0; i < 4; ++i) {
    float s[4] = {0,0,0,0}, s2[4] = {0,0,0,0};
    if (needln) {
      #pragma unroll
      for (int j = 0; j < 4; ++j)
        #pragma unroll
        for (int reg = 0; reg < 4; ++reg) {
          float v = acc[i][j][reg];
          s[reg] += v; s2[reg] += v*v;
        }
      #pragma unroll
      for (int reg = 0; reg < 4; ++reg)
        #pragma unroll
        for (int off = 1; off < 16; off <<= 1) {
          s[reg]  += __shfl_xor(s[reg],  off);
          s2[reg] += __shfl_xor(s2[reg], off);
        }
    }
    #pragma unroll
    for (int reg = 0; reg < 4; ++reg) {
      int r = row0 + wm*64 + i*16 + quad*4 + reg;
      if (r >= MVALID) continue;
      float mu = s[reg]*(1.f/64.f);
      float rs = rsqrtf(fmaxf(s2[reg]*(1.f/64.f) - mu*mu, 0.f) + 1e-5f);
      int b = row2img(r), l = r - c_off[b];
      #pragma unroll
      for (int j = 0; j < 4; ++j) {
        int dh = j*16 + l15;
        float v = acc[i][j][reg];
        if (needln) v = (v - mu)*rs*gain[dh];
        if (POOL) {
          KV[(size_t)r*1024 + unit*64 + dh] = v;
        } else {
          int h = unit & 7;
          size_t dst = ((size_t)(b*8+h)*LMAXS + l)*64 + dh;
          if (unit < 8)       Qh[dst] = f2bf(v);
          else if (unit < 16) Kh[dst] = f2bf(v);
          else                Vh[dst] = f2bf(v);
        }
      }
    }
  }
}

// ---- fused split-K reduce + residual + LayerNorm: T (+= P0+P1); Y = bf16(LN(T)*g) ----
__global__ __launch_bounds__(256) void row_ln_add2_k(
    float* __restrict__ T, const float* __restrict__ P0, const float* __restrict__ P1,
    const float* __restrict__ g, ushort* __restrict__ Y) {
  __shared__ float red[8];
  size_t base = (size_t)blockIdx.x * DIM;
  float v0 = T[base + threadIdx.x], v1 = T[base + threadIdx.x + 256];
  if (P0) {
    v0 += P0[base + threadIdx.x] + P1[base + threadIdx.x];
    v1 += P0[base + threadIdx.x + 256] + P1[base + threadIdx.x + 256];
    T[base + threadIdx.x] = v0;
    T[base + threadIdx.x + 256] = v1;
  }
  float s = v0 + v1, s2 = v0*v0 + v1*v1;
  reduce2_256(s, s2, red);
  float mu = s*(1.f/DIM), rs = rsqrtf(fmaxf(s2*(1.f/DIM) - mu*mu, 0.f) + 1e-5f);
  Y[base + threadIdx.x]       = f2bf((v0-mu)*rs*g[threadIdx.x]);
  Y[base + threadIdx.x + 256] = f2bf((v1-mu)*rs*g[threadIdx.x + 256]);
}

// ---- LN2 + bias + pos embed, packed, in place on fp32 T ----
__global__ __launch_bounds__(256) void ln2_pos_k(
    float* __restrict__ T, const float* __restrict__ g, const float* __restrict__ bb,
    const float* __restrict__ ph, const float* __restrict__ pw) {
  int r = blockIdx.x;
  float* x = T + (size_t)r * DIM;
  if (r >= MVALID) {
    for (int i = threadIdx.x; i < DIM; i += 256) x[i] = 0.f;
    return;
  }
  int b = row2img(r), l = r - c_off[b];
  __shared__ float red[8];
  int wgrid = c_w[b];
  int hi = l / wgrid, wi = l % wgrid;
  float s=0.f, s2=0.f;
  for (int i = threadIdx.x; i < DIM; i += 256) { float v = x[i]; s+=v; s2+=v*v; }
  reduce2_256(s, s2, red);
  float mu = s*(1.f/DIM), rs = rsqrtf(fmaxf(s2*(1.f/DIM)-mu*mu, 0.f)+1e-5f);
  for (int i = threadIdx.x; i < DIM; i += 256)
    x[i] = (x[i]-mu)*rs*g[i] + bb[i] + ph[hi*DIM+i] + pw[wi*DIM+i];
}

// ---- V transpose per head: Vh [bh][l][64] -> VhT [bh][64][LMAX] ----
__global__ __launch_bounds__(256) void vtrans_k(
    const ushort* __restrict__ Vh, ushort* __restrict__ VhT) {
  int bh = blockIdx.x, b = bh >> 3;
  int lt = blockIdx.y;
  if (lt*64 >= c_L[b]) return;
  __shared__ ushort t[64][72];
  int tid = threadIdx.x;
  int row = tid >> 2, seg = (tid & 3)*16;
  const ushort* src = Vh + ((size_t)bh*LMAXS + lt*64 + row)*64 + seg;
  *(short8*)&t[row][seg]   = *(const short8*)src;
  *(short8*)&t[row][seg+8] = *(const short8*)(src+8);
  __syncthreads();
  int dh = tid >> 2, ks = (tid & 3)*16;
  short8 o0, o1;
  #pragma unroll
  for (int jj = 0; jj < 8; ++jj) o0[jj] = (short)t[ks+jj][dh];
  #pragma unroll
  for (int jj = 0; jj < 8; ++jj) o1[jj] = (short)t[ks+8+jj][dh];
  ushort* dst = VhT + ((size_t)bh*64 + dh)*LMAXS + lt*64 + ks;
  *(short8*)dst     = o0;
  *(short8*)(dst+8) = o1;
}

// ---- bf16 MFMA flash attention (max-free softmax, swizzled async staging) ----
__global__ __launch_bounds__(256) void attn_mfma_k(
    const ushort* __restrict__ Qh, const ushort* __restrict__ Kh,
    const ushort* __restrict__ VhT, ushort* __restrict__ O) {
  int bh = blockIdx.x, b = bh >> 3, h = bh & 7;
  int Lb = c_L[b];
  int qt = blockIdx.y;
  if (qt * 64 >= Lb) return;
  __shared__ ushort Ks[64*64];            // swizzled: row r, seg s at r*64 + (s^(r&7))*8
  __shared__ ushort Vt[64*64];
  __shared__ ushort Pb[4][16][68];
  int tid = threadIdx.x, wv = tid >> 6, lane = tid & 63;
  int quad = lane >> 4, l15 = lane & 15;
  int sw = l15 & 7;
  int segA = (quad ^ sw) * 8, segB = segA ^ 32;
  int q0 = qt*64 + wv*16;
  bool active = q0 < Lb;
  const ushort* qhb = Qh + (size_t)bh * LMAXS * DH;
  const ushort* khb = Kh + (size_t)bh * LMAXS * DH;
  const ushort* vtb = VhT + (size_t)bh * DH * LMAXS;
  short8 aq0 = {}, aq1 = {};
  if (active) {
    const ushort* qp = qhb + (size_t)(q0 + l15) * DH;
    aq0 = *(const short8*)(qp + quad*8);
    aq1 = *(const short8*)(qp + 32 + quad*8);
  }
  int blk0 = tid, blk1 = tid + 256;
  int kr0 = blk0 >> 3, s0 = ((blk0 & 7) ^ (kr0 & 7)) * 8;
  int kr1 = blk1 >> 3, s1 = ((blk1 & 7) ^ (kr1 & 7)) * 8;
  const ushort* kg0 = khb + kr0*DH + s0;
  const ushort* kg1 = khb + kr1*DH + s1;
  const ushort* vg0 = vtb + (size_t)kr0*LMAXS + s0;
  const ushort* vg1 = vtb + (size_t)kr1*LMAXS + s1;
  float lsum[4] = {0.f,0.f,0.f,0.f};
  floatx4 o[4] = {};
  for (int kc = 0; kc < Lb; kc += 64) {
    __syncthreads();
    GLOAD_LDS16(kg0 + kc*DH, &Ks[blk0*8]);
    GLOAD_LDS16(kg1 + kc*DH, &Ks[blk1*8]);
    GLOAD_LDS16(vg0 + kc,    &Vt[blk0*8]);
    GLOAD_LDS16(vg1 + kc,    &Vt[blk1*8]);
    __syncthreads();
    if (!active) continue;
    bool tail = (kc + 64 > Lb);
    #pragma unroll
    for (int kb = 0; kb < 4; ++kb) {
      int krow = (kb*16 + l15) * 64;
      floatx4 s = {};
      s = __builtin_amdgcn_mfma_f32_16x16x32_bf16(aq0, *(const short8*)&Ks[krow + segA], s, 0,0,0);
      s = __builtin_amdgcn_mfma_f32_16x16x32_bf16(aq1, *(const short8*)&Ks[krow + segB], s, 0,0,0);
      #pragma unroll
      for (int reg = 0; reg < 4; ++reg) {
        float x = s[reg] * 0.125f;
        if (tail && (kc + kb*16 + l15 >= Lb)) x = -1e9f;
        float p = __expf(x);                 // |x|<=8 for valid keys after unit-gain head-LN
        lsum[reg] += p;
        Pb[wv][quad*4+reg][kb*16+l15] = f2bf(p);
      }
    }
    short8 a0 = *(const short8*)&Pb[wv][l15][quad*8];
    short8 a1 = *(const short8*)&Pb[wv][l15][32+quad*8];
    #pragma unroll
    for (int nb = 0; nb < 4; ++nb) {
      int vrow = (nb*16 + l15) * 64;
      o[nb] = __builtin_amdgcn_mfma_f32_16x16x32_bf16(a0, *(const short8*)&Vt[vrow + segA], o[nb], 0,0,0);
      o[nb] = __builtin_amdgcn_mfma_f32_16x16x32_bf16(a1, *(const short8*)&Vt[vrow + segB], o[nb], 0,0,0);
    }
  }
  if (active) {
    float inv[4];
    #pragma unroll
    for (int reg = 0; reg < 4; ++reg) {
      float s = lsum[reg];
      s += __shfl_xor(s,1); s += __shfl_xor(s,2); s += __shfl_xor(s,4); s += __shfl_xor(s,8);
      inv[reg] = 1.f / s;
    }
    int rbase = c_off[b] + q0 + quad*4;
    #pragma unroll
    for (int nb = 0; nb < 4; ++nb)
      #pragma unroll
      for (int reg = 0; reg < 4; ++reg)
        O[(size_t)(rbase+reg)*DIM + h*DH + nb*16 + l15] = f2bf(o[nb][reg] * inv[reg]);
  }
}

// ---- pool query prep A: qp = LN(pool_q) @ pool_wq^T, column-parallel ----
__global__ __launch_bounds__(256) void pool_prep_a_k(
    const float* __restrict__ pq, const float* __restrict__ pln,
    const float* __restrict__ pwq, float* __restrict__ qp) {
  __shared__ float qln[DIM];
  __shared__ float red[8];
  int tid = threadIdx.x;
  float s=0.f, s2=0.f;
  for (int i=tid;i<DIM;i+=256){ float v=pq[i]; s+=v; s2+=v*v; }
  reduce2_256(s, s2, red);
  float mu=s*(1.f/DIM), rs=rsqrtf(fmaxf(s2*(1.f/DIM)-mu*mu,0.f)+1e-5f);
  for (int i=tid;i<DIM;i+=256) qln[i]=(pq[i]-mu)*rs*pln[i];
  __syncthreads();
  int n = blockIdx.x*64 + (tid>>2);
  int kq = (tid&3)*128;
  const float4* wr = (const float4*)(pwq + (size_t)n*DIM + kq);
  float a=0.f;
  #pragma unroll
  for (int k=0;k<32;++k) {
    float4 w4 = wr[k];
    float4 q4 = *(const float4*)&qln[kq + k*4];
    a += w4.x*q4.x + w4.y*q4.y + w4.z*q4.z + w4.w*q4.w;
  }
  a += __shfl_xor(a,1); a += __shfl_xor(a,2);
  if ((tid&3)==0) qp[n]=a;
}

// ---- pool query prep B: per-head LN on qp -> qpool ----
__global__ __launch_bounds__(512) void pool_prep_b_k(
    const float* __restrict__ qp, const float* __restrict__ pqn, float* __restrict__ qpool) {
  int h = threadIdx.x >> 6, lane = threadIdx.x & 63;
  float v = qp[h*64 + lane];
  float s = v, s2 = v*v;
  #pragma unroll
  for (int off=32; off; off>>=1) { s += __shfl_xor(s,off); s2 += __shfl_xor(s2,off); }
  float mu = s*(1.f/64), rs = rsqrtf(fmaxf(s2*(1.f/64)-mu*mu, 0.f)+1e-5f);
  qpool[h*64+lane] = (v-mu)*rs*pqn[lane];
}

// ---- pooling cross-attention, phase 1: per (bh, key-chunk) partials ----
__global__ __launch_bounds__(256) void pool_attn_part_k(
    const float* __restrict__ qpool, const float* __restrict__ KV,
    float* __restrict__ PART) {
  __shared__ float qh[DH];
  __shared__ float ps[256];
  __shared__ float op[4][DH];
  __shared__ float red[8];
  int bh = blockIdx.x, c = blockIdx.y;
  int b = bh>>3, h = bh&7;
  int Lb = c_L[b];
  int tid = threadIdx.x;
  if (tid < DH) qh[tid] = qpool[h*DH + tid];
  __syncthreads();
  int kk = c*256 + tid;
  float p = 0.f;
  if (kk < Lb) {
    const float4* kp = (const float4*)(KV + (size_t)(c_off[b]+kk)*1024 + h*DH);
    float a = 0.f;
    #pragma unroll
    for (int dd=0; dd<16; ++dd) {
      float4 kv = kp[dd];
      a += kv.x*qh[dd*4] + kv.y*qh[dd*4+1] + kv.z*qh[dd*4+2] + kv.w*qh[dd*4+3];
    }
    p = __expf(a*0.125f);
  }
  ps[tid] = p;
  float s = p, s2 = 0.f;
  reduce2_256(s, s2, red);
  int wvv = tid >> 6, lane = tid & 63;
  float o = 0.f;
  int kb = c*256 + wvv*64;
  const float* vb = KV + (size_t)c_off[b]*1024 + 512 + h*DH + lane;
  for (int j = 0; j < 64; ++j) {
    int key = kb + j;
    if (key < Lb) o += ps[wvv*64+j] * vb[(size_t)key*1024];
  }
  op[wvv][lane] = o;
  __syncthreads();
  if (tid < DH)
    PART[((size_t)bh*4 + c)*66 + tid] = op[0][tid]+op[1][tid]+op[2][tid]+op[3][tid];
  if (tid == 64)
    PART[((size_t)bh*4 + c)*66 + 64] = s;
}

// ---- pooling cross-attention, phase 2: combine chunks ----
__global__ __launch_bounds__(64) void pool_attn_comb_k(
    const float* __restrict__ PART, float* __restrict__ O) {
  int bh = blockIdx.x, b = bh>>3, h = bh&7, d = threadIdx.x;
  float o = 0.f, sum = 0.f;
  #pragma unroll
  for (int c = 0; c < 4; ++c) {
    o   += PART[((size_t)bh*4 + c)*66 + d];
    sum += PART[((size_t)bh*4 + c)*66 + 64];
  }
  O[(size_t)b*DIM + h*DH + d] = o / sum;
}

// ---- tiny projection Y[8,512] = X[8,512] @ W[512,512]^T, column-split ----
__global__ __launch_bounds__(256) void proj512_k(
    const float* __restrict__ X, const float* __restrict__ W, float* __restrict__ Y) {
  __shared__ float xr[DIM];
  int b = blockIdx.x, tid = threadIdx.x;
  for (int i=tid;i<DIM;i+=256) xr[i] = X[(size_t)b*DIM+i];
  __syncthreads();
  if (tid < 128) {
    int n = blockIdx.y*128 + tid;
    const float4* wr = (const float4*)(W + (size_t)n*DIM);
    float a=0.f;
    for (int k=0;k<DIM/4;++k) { float4 w4 = wr[k]; a += w4.x*xr[k*4]+w4.y*xr[k*4+1]+w4.z*xr[k*4+2]+w4.w*xr[k*4+3]; }
    Y[(size_t)b*DIM+n]=a;
  }
}

// ---- final LN + classifier head, column-split ----
__global__ __launch_bounds__(256) void head_out_k(
    const float* __restrict__ X, const float* __restrict__ g,
    const float* __restrict__ W, float* __restrict__ out) {
  __shared__ float xr[DIM];
  __shared__ float red[8];
  int b = blockIdx.x, tid = threadIdx.x;
  float s=0.f, s2=0.f;
  for (int i=tid;i<DIM;i+=256){ float v=X[(size_t)b*DIM+i]; s+=v; s2+=v*v; }
  reduce2_256(s, s2, red);
  float mu=s*(1.f/DIM), rs=rsqrtf(fmaxf(s2*(1.f/DIM)-mu*mu,0.f)+1e-5f);
  for (int i=tid;i<DIM;i+=256) xr[i]=(X[(size_t)b*DIM+i]-mu)*rs*g[i];
  __syncthreads();
  if (tid < 125) {
    int n = blockIdx.y*125 + tid;
    const float4* wr = (const float4*)(W + (size_t)n*DIM);
    float a=0.f;
    for (int k=0;k<DIM/4;++k){ float4 w4=wr[k]; a += w4.x*xr[k*4]+w4.y*xr[k*4+1]+w4.z*xr[k*4+2]+w4.w*xr[k*4+3]; }
    out[(size_t)b*NC+n]=a;
  }
}

extern "C" void kernel_launch(void* const* d_in, const int* in_sizes, int n_in,
                              void* d_out, int out_size, void* d_ws, size_t ws_size,
                              hipStream_t stream) {
  const float* images  = (const float*)d_in[0];
  const float* pe_ln1_w= (const float*)d_in[1];
  const float* pe_ln1_b= (const float*)d_in[2];
  const float* pe_w    = (const float*)d_in[3];
  const float* pe_b    = (const float*)d_in[4];
  const float* pe_ln2_w= (const float*)d_in[5];
  const float* pe_ln2_b= (const float*)d_in[6];
  const float* pos_h   = (const float*)d_in[7];
  const float* pos_w   = (const float*)d_in[8];
  const float* attn_ln = (const float*)d_in[9];
  const float* wq      = (const float*)d_in[10];
  const float* wk      = (const float*)d_in[11];
  const float* wvp     = (const float*)d_in[12];
  const float* qn      = (const float*)d_in[13];
  const float* kn      = (const float*)d_in[14];
  const float* wo      = (const float*)d_in[15];
  const float* ff_ln   = (const float*)d_in[16];
  const float* ff_w1   = (const float*)d_in[17];
  const float* ff_b1   = (const float*)d_in[18];
  const float* ff_w2   = (const float*)d_in[19];
  const float* ff_b2   = (const float*)d_in[20];
  const float* final_ln= (const float*)d_in[21];
  const float* pool_q  = (const float*)d_in[22];
  const float* pool_ln = (const float*)d_in[23];
  const float* pool_wq = (const float*)d_in[24];
  const float* pool_wk = (const float*)d_in[25];
  const float* pool_wv = (const float*)d_in[26];
  const float* pool_qn = (const float*)d_in[27];
  const float* pool_kn = (const float*)d_in[28];
  const float* pool_wo = (const float*)d_in[29];
  const float* head_ln = (const float*)d_in[30];
  const float* head_w  = (const float*)d_in[31];
  (void)ws_size; (void)in_sizes; (void)n_in; (void)out_size;

  char* p = (char*)d_ws;
  ushort* WQKVc = (ushort*)p; p += (size_t)6*1536*512*2;   // 9.44 MB
  ushort* WOc   = (ushort*)p; p += (size_t)6*512*512*2;    // 3.15 MB
  ushort* W1c   = (ushort*)p; p += (size_t)6*2048*512*2;   // 12.6 MB
  ushort* W2c   = (ushort*)p; p += (size_t)6*512*2048*2;   // 12.6 MB
  ushort* PEWc  = (ushort*)p; p += (size_t)512*768*2;      // 0.79 MB
  ushort* PKVc  = (ushort*)p; p += (size_t)1024*512*2;     // 1.05 MB
  float*  T     = (float*)p;  p += (size_t)MPACK*DIM*4;    // 11.0 MB
  ushort* XN    = (ushort*)p; p += (size_t)MPACK*DIM*2;    // 5.5 MB
  float*  KVb   = (float*)p;  p += (size_t)MPACK*1024*4;   // 22.0 MB (pool KV; P0/P1 split-K partials alias)
  float*  P0    = KVb;
  float*  P1    = KVb + (size_t)MPACK*DIM;
  ushort* Qh    = (ushort*)p; p += (size_t)64*LMAXS*DH*2;  // 8.4 MB
  ushort* Kh    = (ushort*)p; p += (size_t)64*LMAXS*DH*2;
  ushort* Vh    = (ushort*)p; p += (size_t)64*LMAXS*DH*2;
  ushort* VhT   = (ushort*)p; p += (size_t)64*64*LMAXS*2;  // 8.4 MB
  ushort* FFH   = (ushort*)p; p += (size_t)MPACK*MLP*2;    // 22.0 MB (aliases TOK, ATTO)
  ushort* TOK   = FFH;
  ushort* ATTO  = FFH;
  float*  QP    = (float*)p;  p += DIM*4;
  float*  QPOOL = (float*)p;  p += DIM*4;
  float*  POOLO = (float*)p;  p += NB*DIM*4;
  float*  POOLED= (float*)p;  p += NB*DIM*4;
  float*  PART  = (float*)p;  p += (size_t)64*4*66*4;

  // ---- weight conversion (same work every call) ----
  cvt_qkv_k<<<(6*1536*512+255)/256, 256, 0, stream>>>(wq, wk, wvp, WQKVc);
  cvt_k<<<(6*512*512+255)/256, 256, 0, stream>>>(wo, WOc, 6*512*512);
  cvt_k<<<(6*2048*512+255)/256, 256, 0, stream>>>(ff_w1, W1c, 6*2048*512);
  cvt_k<<<(6*512*2048+255)/256, 256, 0, stream>>>(ff_w2, W2c, 6*512*2048);
  cvt_k<<<(512*768+255)/256, 256, 0, stream>>>(pe_w, PEWc, 512*768);
  cvt_pool_k<<<(1024*512+255)/256, 256, 0, stream>>>(pool_wk, pool_wv, PKVc);

  // ---- patch embed (packed) ----
  pack_ln1_k<<<MPACK, 256, 0, stream>>>(images, pe_ln1_w, pe_ln1_b, TOK);
  gemm_bf<0,0><<<dim3(4, MPACK/128), 256, 0, stream>>>(TOK, PEWc, pe_b, T, MPACK, DIM, PDIM);
  ln2_pos_k<<<MPACK, 256, 0, stream>>>(T, pe_ln2_w, pe_ln2_b, pos_h, pos_w);

  // ---- transformer layers ----
  for (int l = 0; l < DEPTH; ++l) {
    // ln1: fuses previous layer's FF2 split-K partials into T
    row_ln_add2_k<<<MPACK, 256, 0, stream>>>(T, l ? P0 : nullptr, P1, attn_ln + l*DIM, XN);
    gemm_qkv_k<0><<<dim3(12, MPACK/128), 256, 0, stream>>>(
        XN, WQKVc + (size_t)l*1536*512, qn + l*DH, kn + l*DH, Qh, Kh, Vh, nullptr, 1536);
    vtrans_k<<<dim3(64, 16), 256, 0, stream>>>(Vh, VhT);
    attn_mfma_k<<<dim3(64, 16), 256, 0, stream>>>(Qh, Kh, VhT, ATTO);
    gemm_bf<0,3><<<dim3(4, MPACK/128, 2), 256, 0, stream>>>(ATTO, WOc + (size_t)l*512*512, nullptr, P0, MPACK, DIM, DIM);
    // ln2: fuses WO partials into T
    row_ln_add2_k<<<MPACK, 256, 0, stream>>>(T, P0, P1, ff_ln + l*DIM, XN);
    gemm_bf<1,2><<<dim3(16, MPACK/128), 256, 0, stream>>>(XN, W1c + (size_t)l*MLP*DIM, ff_b1 + l*MLP, FFH, MPACK, MLP, DIM);
    gemm_bf<0,3><<<dim3(4, MPACK/128, 2), 256, 0, stream>>>(FFH, W2c + (size_t)l*DIM*MLP, ff_b2 + l*DIM, P0, MPACK, DIM, MLP);
  }

  // ---- pooling head (final LN fuses last FF2 partials) ----
  row_ln_add2_k<<<MPACK, 256, 0, stream>>>(T, P0, P1, final_ln, XN);
  pool_prep_a_k<<<8, 256, 0, stream>>>(pool_q, pool_ln, pool_wq, QP);
  pool_prep_b_k<<<1, 512, 0, stream>>>(QP, pool_qn, QPOOL);
  gemm_qkv_k<1><<<dim3(8, MPACK/128), 256, 0, stream>>>(
      XN, PKVc, pool_kn, nullptr, nullptr, nullptr, nullptr, KVb, 1024);
  pool_attn_part_k<<<dim3(64, 4), 256, 0, stream>>>(QPOOL, KVb, PART);
  pool_attn_comb_k<<<64, 64, 0, stream>>>(PART, POOLO);
  proj512_k<<<dim3(8, 4), 256, 0, stream>>>(POOLO, pool_wo, POOLED);
  head_out_k<<<dim3(8, 8), 256, 0, stream>>>(POOLED, head_ln, head_w, (float*)d_out);
}